// Round 2
// baseline (1081.512 us; speedup 1.0000x reference)
//
#include <hip/hip_runtime.h>
#include <hip/hip_bf16.h>

#define N_NODES 100000
#define E_EDGES 1600000
#define ETOT    1700000   // E + N self-loops
#define F_IN    128
#define HC      64
#define OUT_C   40
#define NEG_SLOPE 0.2f
#define BN_EPS  1e-5f

// fp32 param block layout (element offsets)
#define P_W1   0
#define P_AS1  8192
#define P_AD1  8256
#define P_B1   8320
#define P_BNG  8384
#define P_BNB  8448
#define P_BNM  8512
#define P_BNV  8576
#define P_W2   8640
#define P_AS2  12736
#define P_AD2  12800
#define P_B2   12864
#define P_WF   12928
#define P_BF   15488
#define P_TOT  15528

// ---------------- dtype detection ----------------
// Samples even 16-bit half-words of node_feat. If the buffer is fp32, those
// half-words are low mantissa bits -> bf16-interp blows past 1e4 (or NaN)
// w.p. ~0.45/sample. If genuinely bf16, values are N(0,1)-scale. 256 samples.
__global__ __launch_bounds__(64) void detect_kernel(const unsigned short* __restrict__ x,
                                                    int* __restrict__ flag) {
    int t = threadIdx.x;
    bool huge = false;
#pragma unroll
    for (int i = 0; i < 4; ++i) {
        unsigned short u = x[(t * 4 + i) * 2];           // even half-word index
        float v = __uint_as_float(((unsigned int)u) << 16);
        if (!(fabsf(v) < 1e4f)) huge = true;             // catches NaN/Inf too
    }
    unsigned long long b = __ballot(huge);
    if (t == 0) *flag = (b != 0ull) ? 1 : 0;             // 1 => fp32 tensors
}

// ---------------- small-param conversion to fp32 ----------------
struct CvtArgs { const void* ptr[14]; int len[14]; };

__global__ __launch_bounds__(256) void cvt_params_kernel(CvtArgs a,
                                                         const int* __restrict__ flag,
                                                         float* __restrict__ dst) {
    int f = *flag;
    int i = blockIdx.x * 256 + threadIdx.x;
    if (i >= P_TOT) return;
    int k = 0, off = 0;
    while (i >= off + a.len[k]) { off += a.len[k]; ++k; }
    int j = i - off;
    float v = f ? ((const float*)a.ptr[k])[j]
                : __bfloat162float(((const __hip_bfloat16*)a.ptr[k])[j]);
    dst[i] = v;
}

// ---------------- CSR build ----------------
__global__ __launch_bounds__(256) void hist_kernel(const int* __restrict__ ei,
                                                   int* __restrict__ deg) {
    int i = blockIdx.x * 256 + threadIdx.x;
    if (i >= ETOT) return;
    int d = (i < E_EDGES) ? ei[E_EDGES + i] : (i - E_EDGES);
    atomicAdd(&deg[d], 1);
}

__global__ __launch_bounds__(1024) void scan_kernel(const int* __restrict__ deg,
                                                    int* __restrict__ row_start,
                                                    int* __restrict__ cursor) {
    __shared__ int sums[1024];
    int t = threadIdx.x;
    const int per = (N_NODES + 1023) / 1024;   // 98
    int lo = t * per;
    int hi = lo + per; if (hi > N_NODES) hi = N_NODES;
    if (hi < lo) hi = lo;
    int s = 0;
    for (int i = lo; i < hi; ++i) s += deg[i];
    sums[t] = s;
    __syncthreads();
    for (int off = 1; off < 1024; off <<= 1) {
        int other = (t >= off) ? sums[t - off] : 0;
        __syncthreads();
        sums[t] += other;
        __syncthreads();
    }
    int run = sums[t] - s;   // exclusive prefix of this thread's chunk
    for (int i = lo; i < hi; ++i) {
        int d = deg[i];
        row_start[i] = run;
        cursor[i]    = run;
        run += d;
    }
    if (t == 1023) row_start[N_NODES] = run;   // == ETOT
}

__global__ __launch_bounds__(256) void scatter_kernel(const int* __restrict__ ei,
                                                      int* __restrict__ cursor,
                                                      int* __restrict__ col) {
    int i = blockIdx.x * 256 + threadIdx.x;
    if (i >= ETOT) return;
    int s, d;
    if (i < E_EDGES) { s = ei[i]; d = ei[E_EDGES + i]; }
    else             { s = d = i - E_EDGES; }
    int pos = atomicAdd(&cursor[d], 1);
    col[pos] = s;
}

// ---------------- GEMM 1: h = x([N,128] bf16 OR fp32) @ W1(fp32 [128,64]) -> fp32 ----------------
// block = 256 = 4 waves; wave handles 4 nodes; lane = output channel.
__global__ __launch_bounds__(256) void gemm1_kernel(const void* __restrict__ x,
                                                    const float* __restrict__ W,
                                                    const int* __restrict__ flag,
                                                    float* __restrict__ h) {
    __shared__ float Wt[64 * 132];   // W transposed [ch][k], padded stride 132
    __shared__ float xs[16 * 128];   // 16 node rows
    int t = threadIdx.x;
    int f = *flag;
    for (int i = t; i < 128 * 64; i += 256) {
        int k = i >> 6, c = i & 63;
        Wt[c * 132 + k] = W[i];
    }
    int base = blockIdx.x * 16;
    if (f) {
        const float* xf = (const float*)x;
        for (int i = t; i < 16 * 128; i += 256)
            xs[i] = xf[base * 128 + i];
    } else {
        const __hip_bfloat16* xb = (const __hip_bfloat16*)x;
        for (int i = t; i < 16 * 128; i += 256)
            xs[i] = __bfloat162float(xb[base * 128 + i]);
    }
    __syncthreads();

    int wid = t >> 6, lane = t & 63;
    const float* xrow = &xs[wid * 4 * 128];
    float acc[4] = {0.f, 0.f, 0.f, 0.f};
    for (int k = 0; k < 128; k += 4) {
        float4 wv = *(const float4*)&Wt[lane * 132 + k];
#pragma unroll
        for (int n = 0; n < 4; ++n) {
            float4 xv = *(const float4*)&xrow[n * 128 + k];
            acc[n] = fmaf(xv.x, wv.x, fmaf(xv.y, wv.y, fmaf(xv.z, wv.z, fmaf(xv.w, wv.w, acc[n]))));
        }
    }
    int n0 = base + wid * 4;
#pragma unroll
    for (int n = 0; n < 4; ++n) h[(size_t)(n0 + n) * 64 + lane] = acc[n];
}

// ---------------- GEMM 2: h = x1(fp32 [N,64]) @ W2(fp32 [64,64]) -> fp32 ----------------
__global__ __launch_bounds__(256) void gemm2_kernel(const float* __restrict__ x1,
                                                    const float* __restrict__ W,
                                                    float* __restrict__ h) {
    __shared__ float Wt[64 * 68];
    __shared__ float xs[16 * 64];
    int t = threadIdx.x;
    for (int i = t; i < 64 * 64; i += 256) {
        int k = i >> 6, c = i & 63;
        Wt[c * 68 + k] = W[i];
    }
    int base = blockIdx.x * 16;
    ((float4*)xs)[t] = ((const float4*)(x1 + (size_t)base * 64))[t];   // 256*16B = 4KB? (16 rows)
    __syncthreads();

    int wid = t >> 6, lane = t & 63;
    const float* xrow = &xs[wid * 4 * 64];
    float acc[4] = {0.f, 0.f, 0.f, 0.f};
    for (int k = 0; k < 64; k += 4) {
        float4 wv = *(const float4*)&Wt[lane * 68 + k];
#pragma unroll
        for (int n = 0; n < 4; ++n) {
            float4 xv = *(const float4*)&xrow[n * 64 + k];
            acc[n] = fmaf(xv.x, wv.x, fmaf(xv.y, wv.y, fmaf(xv.z, wv.z, fmaf(xv.w, wv.w, acc[n]))));
        }
    }
    int n0 = base + wid * 4;
#pragma unroll
    for (int n = 0; n < 4; ++n) h[(size_t)(n0 + n) * 64 + lane] = acc[n];
}

// ---------------- alpha: as[n,h] = sum_c h[n,h,c]*a_s[h,c]; same for ad ----------------
// wave per node, lane = (head, c)
__global__ __launch_bounds__(256) void alpha_kernel(const float* __restrict__ h,
                                                    const float* __restrict__ a_s,
                                                    const float* __restrict__ a_d,
                                                    float* __restrict__ as_,
                                                    float* __restrict__ ad_) {
    int t = threadIdx.x, wid = t >> 6, lane = t & 63;
    int n = blockIdx.x * 4 + wid;
    float hv = h[(size_t)n * 64 + lane];
    float vs = hv * a_s[lane];   // a_s laid out [head][c] == [64]
    float vd = hv * a_d[lane];
    for (int off = 16; off > 0; off >>= 1) {
        vs += __shfl_xor(vs, off, 64);
        vd += __shfl_xor(vd, off, 64);
    }
    int head = lane >> 5, c = lane & 31;
    if (c == 0) {
        as_[n * 2 + head] = vs;
        ad_[n * 2 + head] = vd;
    }
}

__device__ __forceinline__ float leaky(float v) { return v > 0.f ? v : NEG_SLOPE * v; }

// ---------------- aggregation layer 1 (+bias, BN eval, ELU) -> x1 fp32 ----------------
// wave per node; lane = (head, channel)
__global__ __launch_bounds__(256) void agg1_kernel(const float* __restrict__ h,
                                                   const float* __restrict__ as_,
                                                   const float* __restrict__ ad_,
                                                   const int* __restrict__ row_start,
                                                   const int* __restrict__ col,
                                                   const float* __restrict__ bias,
                                                   const float* __restrict__ bn_g,
                                                   const float* __restrict__ bn_b,
                                                   const float* __restrict__ bn_m,
                                                   const float* __restrict__ bn_v,
                                                   float* __restrict__ x1) {
    int t = threadIdx.x, wid = t >> 6, lane = t & 63;
    int v = blockIdx.x * 4 + wid;
    int rs = row_start[v], re = row_start[v + 1];
    int head = lane >> 5;
    float adv0 = ad_[v * 2], adv1 = ad_[v * 2 + 1];

    float m0 = -1e30f, m1 = -1e30f;
    for (int e = rs + lane; e < re; e += 64) {
        int s = col[e];
        m0 = fmaxf(m0, leaky(as_[s * 2] + adv0));
        m1 = fmaxf(m1, leaky(as_[s * 2 + 1] + adv1));
    }
    for (int off = 32; off > 0; off >>= 1) {
        m0 = fmaxf(m0, __shfl_xor(m0, off, 64));
        m1 = fmaxf(m1, __shfl_xor(m1, off, 64));
    }
    float s0 = 0.f, s1 = 0.f;
    for (int e = rs + lane; e < re; e += 64) {
        int s = col[e];
        s0 += __expf(leaky(as_[s * 2] + adv0) - m0);
        s1 += __expf(leaky(as_[s * 2 + 1] + adv1) - m1);
    }
    for (int off = 32; off > 0; off >>= 1) {
        s0 += __shfl_xor(s0, off, 64);
        s1 += __shfl_xor(s1, off, 64);
    }
    float rd0 = 1.f / (s0 + 1e-16f), rd1 = 1.f / (s1 + 1e-16f);
    float mh  = head ? m1 : m0;
    float rdh = head ? rd1 : rd0;
    float advh = head ? adv1 : adv0;

    float acc = 0.f;
    for (int e = rs; e < re; ++e) {
        int s = col[e];
        float w = __expf(leaky(as_[s * 2 + head] + advh) - mh) * rdh;
        acc = fmaf(w, h[(size_t)s * 64 + lane], acc);
    }
    float r = acc + bias[lane];
    float scale = bn_g[lane] * rsqrtf(bn_v[lane] + BN_EPS);
    r = (r - bn_m[lane]) * scale + bn_b[lane];
    r = r > 0.f ? r : expm1f(r);   // ELU
    x1[(size_t)v * 64 + lane] = r;
}

// ---------------- aggregation layer 2 + JK max + final projection -> out [N,40] ----------------
__global__ __launch_bounds__(256) void agg2_kernel(const float* __restrict__ h,
                                                   const float* __restrict__ as_,
                                                   const float* __restrict__ ad_,
                                                   const int* __restrict__ row_start,
                                                   const int* __restrict__ col,
                                                   const float* __restrict__ bias,
                                                   const float* __restrict__ x1,
                                                   const float* __restrict__ Wf,
                                                   const float* __restrict__ bf_,
                                                   const int* __restrict__ flag,
                                                   void* __restrict__ out) {
    __shared__ float Wfs[64 * 40];
    int t = threadIdx.x;
    for (int i = t; i < 64 * 40; i += 256) Wfs[i] = Wf[i];
    __syncthreads();

    int wid = t >> 6, lane = t & 63;
    int v = blockIdx.x * 4 + wid;
    int rs = row_start[v], re = row_start[v + 1];
    int head = lane >> 5;
    float adv0 = ad_[v * 2], adv1 = ad_[v * 2 + 1];

    float m0 = -1e30f, m1 = -1e30f;
    for (int e = rs + lane; e < re; e += 64) {
        int s = col[e];
        m0 = fmaxf(m0, leaky(as_[s * 2] + adv0));
        m1 = fmaxf(m1, leaky(as_[s * 2 + 1] + adv1));
    }
    for (int off = 32; off > 0; off >>= 1) {
        m0 = fmaxf(m0, __shfl_xor(m0, off, 64));
        m1 = fmaxf(m1, __shfl_xor(m1, off, 64));
    }
    float s0 = 0.f, s1 = 0.f;
    for (int e = rs + lane; e < re; e += 64) {
        int s = col[e];
        s0 += __expf(leaky(as_[s * 2] + adv0) - m0);
        s1 += __expf(leaky(as_[s * 2 + 1] + adv1) - m1);
    }
    for (int off = 32; off > 0; off >>= 1) {
        s0 += __shfl_xor(s0, off, 64);
        s1 += __shfl_xor(s1, off, 64);
    }
    float rd0 = 1.f / (s0 + 1e-16f), rd1 = 1.f / (s1 + 1e-16f);
    float mh  = head ? m1 : m0;
    float rdh = head ? rd1 : rd0;
    float advh = head ? adv1 : adv0;

    float acc = 0.f;
    for (int e = rs; e < re; ++e) {
        int s = col[e];
        float w = __expf(leaky(as_[s * 2 + head] + advh) - mh) * rdh;
        acc = fmaf(w, h[(size_t)s * 64 + lane], acc);
    }
    float x2 = acc + bias[lane];                      // layer-2 output (no BN/ELU)
    float xj = fmaxf(x1[(size_t)v * 64 + lane], x2);  // JumpingKnowledge max

    // out[v, o] = sum_c xj[c] * Wf[c, o] + bf[o], o < 40
    int ol = lane < 40 ? lane : 39;
    float po = 0.f;
    for (int c = 0; c < 64; ++c)
        po = fmaf(__shfl(xj, c, 64), Wfs[c * 40 + ol], po);
    if (lane < 40) {
        float r = po + bf_[ol];
        if (*flag) ((float*)out)[(size_t)v * 40 + lane] = r;
        else ((__hip_bfloat16*)out)[(size_t)v * 40 + lane] = __float2bfloat16(r);
    }
}

extern "C" void kernel_launch(void* const* d_in, const int* in_sizes, int n_in,
                              void* d_out, int out_size, void* d_ws, size_t ws_size,
                              hipStream_t stream) {
    (void)in_sizes; (void)n_in; (void)out_size; (void)ws_size;
    const void* node_feat = d_in[0];
    const int*  edge_idx  = (const int*)d_in[1];

    char* ws = (char*)d_ws;
    size_t off = 0;
    auto alloc = [&](size_t bytes) -> void* {
        void* p = ws + off;
        off += (bytes + 255) & ~(size_t)255;
        return p;
    };
    float* h   = (float*)alloc((size_t)N_NODES * 64 * 4);   // 25.6 MB (reused both layers)
    float* x1  = (float*)alloc((size_t)N_NODES * 64 * 4);   // 25.6 MB
    float* as_ = (float*)alloc((size_t)N_NODES * 2 * 4);
    float* ad_ = (float*)alloc((size_t)N_NODES * 2 * 4);
    int* deg       = (int*)alloc((size_t)N_NODES * 4);
    int* row_start = (int*)alloc((size_t)(N_NODES + 1) * 4);
    int* cursor    = (int*)alloc((size_t)N_NODES * 4);
    int* col       = (int*)alloc((size_t)ETOT * 4);         // 6.8 MB
    float* prm     = (float*)alloc((size_t)P_TOT * 4);      // fp32 param block
    int* flag      = (int*)alloc(256);

    // dtype detect + param conversion
    detect_kernel<<<1, 64, 0, stream>>>((const unsigned short*)node_feat, flag);
    CvtArgs ca;
    const int lens[14] = {8192, 64, 64, 64, 64, 64, 64, 64, 4096, 64, 64, 64, 2560, 40};
    for (int i = 0; i < 14; ++i) { ca.ptr[i] = d_in[i + 2]; ca.len[i] = lens[i]; }
    cvt_params_kernel<<<(P_TOT + 255) / 256, 256, 0, stream>>>(ca, flag, prm);

    const int eb = (ETOT + 255) / 256;   // 6641

    // CSR build (same graph for both layers)
    hipMemsetAsync(deg, 0, (size_t)N_NODES * 4, stream);
    hist_kernel<<<eb, 256, 0, stream>>>(edge_idx, deg);
    scan_kernel<<<1, 1024, 0, stream>>>(deg, row_start, cursor);
    scatter_kernel<<<eb, 256, 0, stream>>>(edge_idx, cursor, col);

    // Layer 1
    gemm1_kernel<<<N_NODES / 16, 256, 0, stream>>>(node_feat, prm + P_W1, flag, h);
    alpha_kernel<<<N_NODES / 4, 256, 0, stream>>>(h, prm + P_AS1, prm + P_AD1, as_, ad_);
    agg1_kernel<<<N_NODES / 4, 256, 0, stream>>>(h, as_, ad_, row_start, col,
                                                 prm + P_B1, prm + P_BNG, prm + P_BNB,
                                                 prm + P_BNM, prm + P_BNV, x1);
    // Layer 2 + JK + projection
    gemm2_kernel<<<N_NODES / 16, 256, 0, stream>>>(x1, prm + P_W2, h);
    alpha_kernel<<<N_NODES / 4, 256, 0, stream>>>(h, prm + P_AS2, prm + P_AD2, as_, ad_);
    agg2_kernel<<<N_NODES / 4, 256, 0, stream>>>(h, as_, ad_, row_start, col,
                                                 prm + P_B2, x1, prm + P_WF, prm + P_BF,
                                                 flag, d_out);
}

// Round 4
// 830.757 us; speedup vs baseline: 1.3018x; 1.3018x over previous
//
#include <hip/hip_runtime.h>
#include <hip/hip_bf16.h>

#define N_NODES 100000
#define E_EDGES 1600000
#define ETOT    1700000   // E + N self-loops
#define NB_SCAN 391       // ceil(N/256)
#define F_IN    128
#define HC      64
#define OUT_C   40
#define NEG_SLOPE 0.2f
#define BN_EPS  1e-5f

// fp32 param block layout (element offsets)
#define P_W1   0
#define P_AS1  8192
#define P_AD1  8256
#define P_B1   8320
#define P_BNG  8384
#define P_BNB  8448
#define P_BNM  8512
#define P_BNV  8576
#define P_W2   8640
#define P_AS2  12736
#define P_AD2  12800
#define P_B2   12864
#define P_WF   12928
#define P_BF   15488
#define P_TOT  15528

// ---------------- dtype detection (worked in R2 — unchanged) ----------------
__global__ __launch_bounds__(64) void detect_kernel(const unsigned short* __restrict__ x,
                                                    int* __restrict__ flag) {
    int t = threadIdx.x;
    bool huge = false;
#pragma unroll
    for (int i = 0; i < 4; ++i) {
        unsigned short u = x[(t * 4 + i) * 2];           // even half-word index
        float v = __uint_as_float(((unsigned int)u) << 16);
        if (!(fabsf(v) < 1e4f)) huge = true;             // catches NaN/Inf too
    }
    unsigned long long b = __ballot(huge);
    if (t == 0) *flag = (b != 0ull) ? 1 : 0;             // 1 => fp32 tensors
}

// ---------------- small-param conversion to fp32 ----------------
struct CvtArgs { const void* ptr[14]; int len[14]; };

__global__ __launch_bounds__(256) void cvt_params_kernel(CvtArgs a,
                                                         const int* __restrict__ flag,
                                                         float* __restrict__ dst) {
    int f = *flag;
    int i = blockIdx.x * 256 + threadIdx.x;
    if (i >= P_TOT) return;
    int k = 0, off = 0;
    while (i >= off + a.len[k]) { off += a.len[k]; ++k; }
    int j = i - off;
    float v = f ? ((const float*)a.ptr[k])[j]
                : __bfloat162float(((const __hip_bfloat16*)a.ptr[k])[j]);
    dst[i] = v;
}

// ---------------- CSR build ----------------
__global__ __launch_bounds__(256) void hist_kernel(const int* __restrict__ ei,
                                                   int* __restrict__ deg) {
    int i = blockIdx.x * 256 + threadIdx.x;
    if (i >= ETOT) return;
    int d = (i < E_EDGES) ? ei[E_EDGES + i] : (i - E_EDGES);
    atomicAdd(&deg[d], 1);
}

// parallel scan: A) per-block sums, B) scan of block sums, C) per-block scan + offset
__global__ __launch_bounds__(256) void scanA_kernel(const int* __restrict__ deg,
                                                    int* __restrict__ bsum) {
    __shared__ int sm[256];
    int t = threadIdx.x;
    int i = blockIdx.x * 256 + t;
    sm[t] = (i < N_NODES) ? deg[i] : 0;
    __syncthreads();
    for (int off = 128; off > 0; off >>= 1) {
        if (t < off) sm[t] += sm[t + off];
        __syncthreads();
    }
    if (t == 0) bsum[blockIdx.x] = sm[0];
}

__global__ __launch_bounds__(512) void scanB_kernel(const int* __restrict__ bsum,
                                                    int* __restrict__ boff,
                                                    int* __restrict__ row_start) {
    __shared__ int sm[512];
    int t = threadIdx.x;
    int v = (t < NB_SCAN) ? bsum[t] : 0;
    sm[t] = v;
    __syncthreads();
    for (int off = 1; off < 512; off <<= 1) {
        int o = (t >= off) ? sm[t - off] : 0;
        __syncthreads();
        sm[t] += o;
        __syncthreads();
    }
    if (t < NB_SCAN) boff[t] = sm[t] - v;          // exclusive
    if (t == NB_SCAN - 1) row_start[N_NODES] = sm[t];   // == ETOT
}

__global__ __launch_bounds__(256) void scanC_kernel(const int* __restrict__ deg,
                                                    const int* __restrict__ boff,
                                                    int* __restrict__ row_start,
                                                    int* __restrict__ cursor) {
    __shared__ int sm[256];
    int t = threadIdx.x;
    int i = blockIdx.x * 256 + t;
    int v = (i < N_NODES) ? deg[i] : 0;
    sm[t] = v;
    __syncthreads();
    for (int off = 1; off < 256; off <<= 1) {
        int o = (t >= off) ? sm[t - off] : 0;
        __syncthreads();
        sm[t] += o;
        __syncthreads();
    }
    if (i < N_NODES) {
        int excl = sm[t] - v + boff[blockIdx.x];
        row_start[i] = excl;
        cursor[i]    = excl;
    }
}

__global__ __launch_bounds__(256) void scatter_kernel(const int* __restrict__ ei,
                                                      int* __restrict__ cursor,
                                                      int* __restrict__ col) {
    int i = blockIdx.x * 256 + threadIdx.x;
    if (i >= ETOT) return;
    int s, d;
    if (i < E_EDGES) { s = ei[i]; d = ei[E_EDGES + i]; }
    else             { s = d = i - E_EDGES; }
    int pos = atomicAdd(&cursor[d], 1);
    col[pos] = s;
}

__device__ __forceinline__ float leaky(float v) { return v > 0.f ? v : NEG_SLOPE * v; }

// head-wise (32-lane-group) sum reduction
__device__ __forceinline__ float red32(float v) {
#pragma unroll
    for (int off = 16; off > 0; off >>= 1) v += __shfl_xor(v, off, 64);
    return v;
}
// full-wave sum reduction
__device__ __forceinline__ float red64(float v) {
#pragma unroll
    for (int off = 32; off > 0; off >>= 1) v += __shfl_xor(v, off, 64);
    return v;
}

// ---------------- GEMM 1 (+fused alpha): h_bf = x @ W1 (bf16 out), as_, ad_ ----------------
// block = 256 = 4 waves; wave handles 4 nodes; lane = output channel.
__global__ __launch_bounds__(256) void gemm1_kernel(const void* __restrict__ x,
                                                    const float* __restrict__ W,
                                                    const float* __restrict__ a_s,
                                                    const float* __restrict__ a_d,
                                                    const int* __restrict__ flag,
                                                    __hip_bfloat16* __restrict__ h_bf,
                                                    float* __restrict__ as_,
                                                    float* __restrict__ ad_) {
    __shared__ float Wt[64 * 132];   // W transposed [ch][k], padded stride 132
    __shared__ float xs[16 * 128];   // 16 node rows
    int t = threadIdx.x;
    int f = *flag;
    for (int i = t; i < 128 * 64; i += 256) {
        int k = i >> 6, c = i & 63;
        Wt[c * 132 + k] = W[i];
    }
    int base = blockIdx.x * 16;
    if (f) {
        const float4* xf = (const float4*)((const float*)x + (size_t)base * 128);
        for (int i = t; i < 16 * 32; i += 256) ((float4*)xs)[i] = xf[i];
    } else {
        const __hip_bfloat16* xb = (const __hip_bfloat16*)x;
        for (int i = t; i < 16 * 128; i += 256)
            xs[i] = __bfloat162float(xb[(size_t)base * 128 + i]);
    }
    __syncthreads();

    int wid = t >> 6, lane = t & 63;
    const float* xrow = &xs[wid * 4 * 128];
    float acc[4] = {0.f, 0.f, 0.f, 0.f};
    for (int k = 0; k < 128; k += 4) {
        float4 wv = *(const float4*)&Wt[lane * 132 + k];
#pragma unroll
        for (int n = 0; n < 4; ++n) {
            float4 xv = *(const float4*)&xrow[n * 128 + k];
            acc[n] = fmaf(xv.x, wv.x, fmaf(xv.y, wv.y, fmaf(xv.z, wv.z, fmaf(xv.w, wv.w, acc[n]))));
        }
    }
    int n0 = base + wid * 4;
    float asl = a_s[lane], adl = a_d[lane];
#pragma unroll
    for (int n = 0; n < 4; ++n) {
        h_bf[(size_t)(n0 + n) * 64 + lane] = __float2bfloat16(acc[n]);
        float vs = red32(acc[n] * asl);
        float vd = red32(acc[n] * adl);
        if ((lane & 31) == 0) {
            as_[(n0 + n) * 2 + (lane >> 5)] = vs;
            ad_[(n0 + n) * 2 + (lane >> 5)] = vd;
        }
    }
}

// ---------------- GEMM 2 (+fused alpha): h_bf = x1(fp32) @ W2, as_, ad_ ----------------
__global__ __launch_bounds__(256) void gemm2_kernel(const float* __restrict__ x1,
                                                    const float* __restrict__ W,
                                                    const float* __restrict__ a_s,
                                                    const float* __restrict__ a_d,
                                                    __hip_bfloat16* __restrict__ h_bf,
                                                    float* __restrict__ as_,
                                                    float* __restrict__ ad_) {
    __shared__ float Wt[64 * 68];
    __shared__ float xs[16 * 64];
    int t = threadIdx.x;
    for (int i = t; i < 64 * 64; i += 256) {
        int k = i >> 6, c = i & 63;
        Wt[c * 68 + k] = W[i];
    }
    int base = blockIdx.x * 16;
    ((float4*)xs)[t] = ((const float4*)(x1 + (size_t)base * 64))[t];
    __syncthreads();

    int wid = t >> 6, lane = t & 63;
    const float* xrow = &xs[wid * 4 * 64];
    float acc[4] = {0.f, 0.f, 0.f, 0.f};
    for (int k = 0; k < 64; k += 4) {
        float4 wv = *(const float4*)&Wt[lane * 68 + k];
#pragma unroll
        for (int n = 0; n < 4; ++n) {
            float4 xv = *(const float4*)&xrow[n * 64 + k];
            acc[n] = fmaf(xv.x, wv.x, fmaf(xv.y, wv.y, fmaf(xv.z, wv.z, fmaf(xv.w, wv.w, acc[n]))));
        }
    }
    int n0 = base + wid * 4;
    float asl = a_s[lane], adl = a_d[lane];
#pragma unroll
    for (int n = 0; n < 4; ++n) {
        h_bf[(size_t)(n0 + n) * 64 + lane] = __float2bfloat16(acc[n]);
        float vs = red32(acc[n] * asl);
        float vd = red32(acc[n] * adl);
        if ((lane & 31) == 0) {
            as_[(n0 + n) * 2 + (lane >> 5)] = vs;
            ad_[(n0 + n) * 2 + (lane >> 5)] = vd;
        }
    }
}

// ---------------- shared aggregation core ----------------
// Computes softmax-weighted gather-sum for node v; lane = (head, channel).
// No max-subtraction: |logits| <= ~10 here, exp is safe in fp32 and softmax is
// mathematically identical.
// NOTE (R3 bug, fixed): every __shfl here MUST execute with all 64 lanes
// active — ds_bpermute returns 0 when the SOURCE lane's EXEC bit is off.
// So we shuffle both heads' weights unconditionally and select with a
// ternary afterwards (v_cndmask, no divergent control flow).
__device__ __forceinline__ float agg_core(const __hip_bfloat16* __restrict__ h_bf,
                                          const float* __restrict__ as_,
                                          const float* __restrict__ ad_,
                                          const int* __restrict__ col,
                                          int v, int rs, int re, int lane) {
    int head = lane >> 5;
    float adv0 = ad_[v * 2], adv1 = ad_[v * 2 + 1];
    int deg = re - rs;
    float acc;
    if (deg <= 64) {
        // lane j owns edge rs+j: gather as_ once, compute both heads' weights
        int sj = 0;
        float w0 = 0.f, w1 = 0.f;
        if (lane < deg) {
            sj = col[rs + lane];
            float2 av = *(const float2*)&as_[sj * 2];
            w0 = __expf(leaky(av.x + adv0));
            w1 = __expf(leaky(av.y + adv1));
        }
        float s0 = red64(w0), s1 = red64(w1);
        float rdh = 1.f / ((head ? s1 : s0) + 1e-16f);
        // weighted gather: s and w via convergent uniform-index shuffles, so
        // the h loads issue back-to-back with no dependent gather/exp per edge
        float a0 = 0.f, a1 = 0.f;
        int j = 0;
        for (; j + 1 < deg; j += 2) {
            int sA = __shfl(sj, j, 64), sB = __shfl(sj, j + 1, 64);
            float w0A = __shfl(w0, j, 64),     w1A = __shfl(w1, j, 64);
            float w0B = __shfl(w0, j + 1, 64), w1B = __shfl(w1, j + 1, 64);
            float wA = head ? w1A : w0A;
            float wB = head ? w1B : w0B;
            float hA = __bfloat162float(h_bf[(size_t)sA * 64 + lane]);
            float hB = __bfloat162float(h_bf[(size_t)sB * 64 + lane]);
            a0 = fmaf(wA, hA, a0);
            a1 = fmaf(wB, hB, a1);
        }
        if (j < deg) {
            int sA = __shfl(sj, j, 64);
            float w0A = __shfl(w0, j, 64), w1A = __shfl(w1, j, 64);
            float wA = head ? w1A : w0A;
            a0 = fmaf(wA, __bfloat162float(h_bf[(size_t)sA * 64 + lane]), a0);
        }
        acc = (a0 + a1) * rdh;
    } else {
        // generic fallback (unused for this graph: max degree << 64)
        float advh = head ? adv1 : adv0;
        float s0 = 0.f, s1 = 0.f;
        for (int e = rs + lane; e < re; e += 64) {
            int s = col[e];
            float2 av = *(const float2*)&as_[s * 2];
            s0 += __expf(leaky(av.x + adv0));
            s1 += __expf(leaky(av.y + adv1));
        }
        s0 = red64(s0); s1 = red64(s1);
        float rdh = 1.f / ((head ? s1 : s0) + 1e-16f);
        float a0 = 0.f;
        for (int e = rs; e < re; ++e) {
            int s = col[e];
            float w = __expf(leaky(as_[s * 2 + head] + advh));
            a0 = fmaf(w, __bfloat162float(h_bf[(size_t)s * 64 + lane]), a0);
        }
        acc = a0 * rdh;
    }
    return acc;
}

// ---------------- aggregation layer 1 (+bias, BN eval, ELU) -> x1 fp32 ----------------
__global__ __launch_bounds__(256) void agg1_kernel(const __hip_bfloat16* __restrict__ h_bf,
                                                   const float* __restrict__ as_,
                                                   const float* __restrict__ ad_,
                                                   const int* __restrict__ row_start,
                                                   const int* __restrict__ col,
                                                   const float* __restrict__ bias,
                                                   const float* __restrict__ bn_g,
                                                   const float* __restrict__ bn_b,
                                                   const float* __restrict__ bn_m,
                                                   const float* __restrict__ bn_v,
                                                   float* __restrict__ x1) {
    int t = threadIdx.x, wid = t >> 6, lane = t & 63;
    int v = blockIdx.x * 4 + wid;
    int rs = row_start[v], re = row_start[v + 1];
    float acc = agg_core(h_bf, as_, ad_, col, v, rs, re, lane);
    float r = acc + bias[lane];
    float scale = bn_g[lane] * rsqrtf(bn_v[lane] + BN_EPS);
    r = (r - bn_m[lane]) * scale + bn_b[lane];
    r = r > 0.f ? r : expm1f(r);   // ELU
    x1[(size_t)v * 64 + lane] = r;
}

// ---------------- aggregation layer 2 + JK max + final projection -> out [N,40] ----------------
__global__ __launch_bounds__(256) void agg2_kernel(const __hip_bfloat16* __restrict__ h_bf,
                                                   const float* __restrict__ as_,
                                                   const float* __restrict__ ad_,
                                                   const int* __restrict__ row_start,
                                                   const int* __restrict__ col,
                                                   const float* __restrict__ bias,
                                                   const float* __restrict__ x1,
                                                   const float* __restrict__ Wf,
                                                   const float* __restrict__ bf_,
                                                   const int* __restrict__ flag,
                                                   void* __restrict__ out) {
    __shared__ float Wfs[64 * 40];
    int t = threadIdx.x;
    for (int i = t; i < 64 * 40; i += 256) Wfs[i] = Wf[i];
    __syncthreads();

    int wid = t >> 6, lane = t & 63;
    int v = blockIdx.x * 4 + wid;
    int rs = row_start[v], re = row_start[v + 1];
    float acc = agg_core(h_bf, as_, ad_, col, v, rs, re, lane);
    float x2 = acc + bias[lane];                      // layer-2 output (no BN/ELU)
    float xj = fmaxf(x1[(size_t)v * 64 + lane], x2);  // JumpingKnowledge max

    // out[v, o] = sum_c xj[c] * Wf[c, o] + bf[o], o < 40   (shuffles convergent)
    int ol = lane < 40 ? lane : 39;
    float po = 0.f;
    for (int c = 0; c < 64; ++c)
        po = fmaf(__shfl(xj, c, 64), Wfs[c * 40 + ol], po);
    if (lane < 40) {
        float r = po + bf_[ol];
        if (*flag) ((float*)out)[(size_t)v * 40 + lane] = r;
        else ((__hip_bfloat16*)out)[(size_t)v * 40 + lane] = __float2bfloat16(r);
    }
}

extern "C" void kernel_launch(void* const* d_in, const int* in_sizes, int n_in,
                              void* d_out, int out_size, void* d_ws, size_t ws_size,
                              hipStream_t stream) {
    (void)in_sizes; (void)n_in; (void)out_size; (void)ws_size;
    const void* node_feat = d_in[0];
    const int*  edge_idx  = (const int*)d_in[1];

    char* ws = (char*)d_ws;
    size_t off = 0;
    auto alloc = [&](size_t bytes) -> void* {
        void* p = ws + off;
        off += (bytes + 255) & ~(size_t)255;
        return p;
    };
    __hip_bfloat16* h_bf = (__hip_bfloat16*)alloc((size_t)N_NODES * 64 * 2);  // 12.8 MB
    float* x1  = (float*)alloc((size_t)N_NODES * 64 * 4);   // 25.6 MB
    float* as_ = (float*)alloc((size_t)N_NODES * 2 * 4);
    float* ad_ = (float*)alloc((size_t)N_NODES * 2 * 4);
    int* deg       = (int*)alloc((size_t)N_NODES * 4);
    int* row_start = (int*)alloc((size_t)(N_NODES + 1) * 4);
    int* cursor    = (int*)alloc((size_t)N_NODES * 4);
    int* col       = (int*)alloc((size_t)ETOT * 4);         // 6.8 MB
    int* bsum      = (int*)alloc((size_t)NB_SCAN * 4);
    int* boff      = (int*)alloc((size_t)NB_SCAN * 4);
    float* prm     = (float*)alloc((size_t)P_TOT * 4);      // fp32 param block
    int* flag      = (int*)alloc(256);

    // dtype detect + param conversion
    detect_kernel<<<1, 64, 0, stream>>>((const unsigned short*)node_feat, flag);
    CvtArgs ca;
    const int lens[14] = {8192, 64, 64, 64, 64, 64, 64, 64, 4096, 64, 64, 64, 2560, 40};
    for (int i = 0; i < 14; ++i) { ca.ptr[i] = d_in[i + 2]; ca.len[i] = lens[i]; }
    cvt_params_kernel<<<(P_TOT + 255) / 256, 256, 0, stream>>>(ca, flag, prm);

    const int eb = (ETOT + 255) / 256;   // 6641

    // CSR build (same graph both layers)
    hipMemsetAsync(deg, 0, (size_t)N_NODES * 4, stream);
    hist_kernel<<<eb, 256, 0, stream>>>(edge_idx, deg);
    scanA_kernel<<<NB_SCAN, 256, 0, stream>>>(deg, bsum);
    scanB_kernel<<<1, 512, 0, stream>>>(bsum, boff, row_start);
    scanC_kernel<<<NB_SCAN, 256, 0, stream>>>(deg, boff, row_start, cursor);
    scatter_kernel<<<eb, 256, 0, stream>>>(edge_idx, cursor, col);

    // Layer 1 (gemm + fused alpha)
    gemm1_kernel<<<N_NODES / 16, 256, 0, stream>>>(node_feat, prm + P_W1,
                                                   prm + P_AS1, prm + P_AD1,
                                                   flag, h_bf, as_, ad_);
    agg1_kernel<<<N_NODES / 4, 256, 0, stream>>>(h_bf, as_, ad_, row_start, col,
                                                 prm + P_B1, prm + P_BNG, prm + P_BNB,
                                                 prm + P_BNM, prm + P_BNV, x1);
    // Layer 2 + JK + projection
    gemm2_kernel<<<N_NODES / 16, 256, 0, stream>>>(x1, prm + P_W2,
                                                   prm + P_AS2, prm + P_AD2,
                                                   h_bf, as_, ad_);
    agg2_kernel<<<N_NODES / 4, 256, 0, stream>>>(h_bf, as_, ad_, row_start, col,
                                                 prm + P_B2, x1, prm + P_WF, prm + P_BF,
                                                 flag, d_out);
}

// Round 5
// 702.707 us; speedup vs baseline: 1.5391x; 1.1822x over previous
//
#include <hip/hip_runtime.h>
#include <hip/hip_bf16.h>

#define N_NODES 100000
#define E_EDGES 1600000
#define ETOT    1700000   // E + N self-loops
#define NB_SCAN 391       // ceil(N/256)
#define F_IN    128
#define HC      64
#define OUT_C   40
#define NEG_SLOPE 0.2f
#define BN_EPS  1e-5f

// fp32 param block layout (element offsets)
#define P_W1   0
#define P_AS1  8192
#define P_AD1  8256
#define P_B1   8320
#define P_BNG  8384
#define P_BNB  8448
#define P_BNM  8512
#define P_BNV  8576
#define P_W2   8640
#define P_AS2  12736
#define P_AD2  12800
#define P_B2   12864
#define P_WF   12928
#define P_BF   15488
#define P_TOT  15528

// ---------------- dtype detection ----------------
__global__ __launch_bounds__(64) void detect_kernel(const unsigned short* __restrict__ x,
                                                    int* __restrict__ flag) {
    int t = threadIdx.x;
    bool huge = false;
#pragma unroll
    for (int i = 0; i < 4; ++i) {
        unsigned short u = x[(t * 4 + i) * 2];           // even half-word index
        float v = __uint_as_float(((unsigned int)u) << 16);
        if (!(fabsf(v) < 1e4f)) huge = true;             // catches NaN/Inf too
    }
    unsigned long long b = __ballot(huge);
    if (t == 0) *flag = (b != 0ull) ? 1 : 0;             // 1 => fp32 tensors
}

// ---------------- small-param conversion to fp32 ----------------
struct CvtArgs { const void* ptr[14]; int len[14]; };

__global__ __launch_bounds__(256) void cvt_params_kernel(CvtArgs a,
                                                         const int* __restrict__ flag,
                                                         float* __restrict__ dst) {
    int f = *flag;
    int i = blockIdx.x * 256 + threadIdx.x;
    if (i >= P_TOT) return;
    int k = 0, off = 0;
    while (i >= off + a.len[k]) { off += a.len[k]; ++k; }
    int j = i - off;
    float v = f ? ((const float*)a.ptr[k])[j]
                : __bfloat162float(((const __hip_bfloat16*)a.ptr[k])[j]);
    dst[i] = v;
}

// ---------------- CSR build ----------------
__global__ __launch_bounds__(256) void hist_kernel(const int* __restrict__ ei,
                                                   int* __restrict__ deg) {
    int i = blockIdx.x * 256 + threadIdx.x;
    if (i >= ETOT) return;
    int d = (i < E_EDGES) ? ei[E_EDGES + i] : (i - E_EDGES);
    atomicAdd(&deg[d], 1);
}

__global__ __launch_bounds__(256) void scanA_kernel(const int* __restrict__ deg,
                                                    int* __restrict__ bsum) {
    __shared__ int sm[256];
    int t = threadIdx.x;
    int i = blockIdx.x * 256 + t;
    sm[t] = (i < N_NODES) ? deg[i] : 0;
    __syncthreads();
    for (int off = 128; off > 0; off >>= 1) {
        if (t < off) sm[t] += sm[t + off];
        __syncthreads();
    }
    if (t == 0) bsum[blockIdx.x] = sm[0];
}

__global__ __launch_bounds__(512) void scanB_kernel(const int* __restrict__ bsum,
                                                    int* __restrict__ boff,
                                                    int* __restrict__ row_start) {
    __shared__ int sm[512];
    int t = threadIdx.x;
    int v = (t < NB_SCAN) ? bsum[t] : 0;
    sm[t] = v;
    __syncthreads();
    for (int off = 1; off < 512; off <<= 1) {
        int o = (t >= off) ? sm[t - off] : 0;
        __syncthreads();
        sm[t] += o;
        __syncthreads();
    }
    if (t < NB_SCAN) boff[t] = sm[t] - v;          // exclusive
    if (t == NB_SCAN - 1) row_start[N_NODES] = sm[t];   // == ETOT
}

__global__ __launch_bounds__(256) void scanC_kernel(const int* __restrict__ deg,
                                                    const int* __restrict__ boff,
                                                    int* __restrict__ row_start,
                                                    int* __restrict__ cursor) {
    __shared__ int sm[256];
    int t = threadIdx.x;
    int i = blockIdx.x * 256 + t;
    int v = (i < N_NODES) ? deg[i] : 0;
    sm[t] = v;
    __syncthreads();
    for (int off = 1; off < 256; off <<= 1) {
        int o = (t >= off) ? sm[t - off] : 0;
        __syncthreads();
        sm[t] += o;
        __syncthreads();
    }
    if (i < N_NODES) {
        int excl = sm[t] - v + boff[blockIdx.x];
        row_start[i] = excl;
        cursor[i]    = excl;
    }
}

__global__ __launch_bounds__(256) void scatter_kernel(const int* __restrict__ ei,
                                                      int* __restrict__ cursor,
                                                      int* __restrict__ col) {
    int i = blockIdx.x * 256 + threadIdx.x;
    if (i >= ETOT) return;
    int s, d;
    if (i < E_EDGES) { s = ei[i]; d = ei[E_EDGES + i]; }
    else             { s = d = i - E_EDGES; }
    int pos = atomicAdd(&cursor[d], 1);
    col[pos] = s;
}

__device__ __forceinline__ float leaky(float v) { return v > 0.f ? v : NEG_SLOPE * v; }

__device__ __forceinline__ float red32(float v) {
#pragma unroll
    for (int off = 16; off > 0; off >>= 1) v += __shfl_xor(v, off, 64);
    return v;
}
__device__ __forceinline__ float red64(float v) {
#pragma unroll
    for (int off = 32; off > 0; off >>= 1) v += __shfl_xor(v, off, 64);
    return v;
}

// ---------------- GEMM 1 (+fused alpha) ----------------
__global__ __launch_bounds__(256) void gemm1_kernel(const void* __restrict__ x,
                                                    const float* __restrict__ W,
                                                    const float* __restrict__ a_s,
                                                    const float* __restrict__ a_d,
                                                    const int* __restrict__ flag,
                                                    __hip_bfloat16* __restrict__ h_bf,
                                                    float* __restrict__ as_,
                                                    float* __restrict__ ad_) {
    __shared__ float Wt[64 * 132];
    __shared__ float xs[16 * 128];
    int t = threadIdx.x;
    int f = *flag;
    for (int i = t; i < 128 * 64; i += 256) {
        int k = i >> 6, c = i & 63;
        Wt[c * 132 + k] = W[i];
    }
    int base = blockIdx.x * 16;
    if (f) {
        const float4* xf = (const float4*)((const float*)x + (size_t)base * 128);
        for (int i = t; i < 16 * 32; i += 256) ((float4*)xs)[i] = xf[i];
    } else {
        const __hip_bfloat16* xb = (const __hip_bfloat16*)x;
        for (int i = t; i < 16 * 128; i += 256)
            xs[i] = __bfloat162float(xb[(size_t)base * 128 + i]);
    }
    __syncthreads();

    int wid = t >> 6, lane = t & 63;
    const float* xrow = &xs[wid * 4 * 128];
    float acc[4] = {0.f, 0.f, 0.f, 0.f};
    for (int k = 0; k < 128; k += 4) {
        float4 wv = *(const float4*)&Wt[lane * 132 + k];
#pragma unroll
        for (int n = 0; n < 4; ++n) {
            float4 xv = *(const float4*)&xrow[n * 128 + k];
            acc[n] = fmaf(xv.x, wv.x, fmaf(xv.y, wv.y, fmaf(xv.z, wv.z, fmaf(xv.w, wv.w, acc[n]))));
        }
    }
    int n0 = base + wid * 4;
    float asl = a_s[lane], adl = a_d[lane];
#pragma unroll
    for (int n = 0; n < 4; ++n) {
        h_bf[(size_t)(n0 + n) * 64 + lane] = __float2bfloat16(acc[n]);
        float vs = red32(acc[n] * asl);
        float vd = red32(acc[n] * adl);
        if ((lane & 31) == 0) {
            as_[(n0 + n) * 2 + (lane >> 5)] = vs;
            ad_[(n0 + n) * 2 + (lane >> 5)] = vd;
        }
    }
}

// ---------------- GEMM 2 (+fused alpha) ----------------
__global__ __launch_bounds__(256) void gemm2_kernel(const float* __restrict__ x1,
                                                    const float* __restrict__ W,
                                                    const float* __restrict__ a_s,
                                                    const float* __restrict__ a_d,
                                                    __hip_bfloat16* __restrict__ h_bf,
                                                    float* __restrict__ as_,
                                                    float* __restrict__ ad_) {
    __shared__ float Wt[64 * 68];
    __shared__ float xs[16 * 64];
    int t = threadIdx.x;
    for (int i = t; i < 64 * 64; i += 256) {
        int k = i >> 6, c = i & 63;
        Wt[c * 68 + k] = W[i];
    }
    int base = blockIdx.x * 16;
    ((float4*)xs)[t] = ((const float4*)(x1 + (size_t)base * 64))[t];
    __syncthreads();

    int wid = t >> 6, lane = t & 63;
    const float* xrow = &xs[wid * 4 * 64];
    float acc[4] = {0.f, 0.f, 0.f, 0.f};
    for (int k = 0; k < 64; k += 4) {
        float4 wv = *(const float4*)&Wt[lane * 68 + k];
#pragma unroll
        for (int n = 0; n < 4; ++n) {
            float4 xv = *(const float4*)&xrow[n * 64 + k];
            acc[n] = fmaf(xv.x, wv.x, fmaf(xv.y, wv.y, fmaf(xv.z, wv.z, fmaf(xv.w, wv.w, acc[n]))));
        }
    }
    int n0 = base + wid * 4;
    float asl = a_s[lane], adl = a_d[lane];
#pragma unroll
    for (int n = 0; n < 4; ++n) {
        h_bf[(size_t)(n0 + n) * 64 + lane] = __float2bfloat16(acc[n]);
        float vs = red32(acc[n] * asl);
        float vd = red32(acc[n] * adl);
        if ((lane & 31) == 0) {
            as_[(n0 + n) * 2 + (lane >> 5)] = vs;
            ad_[(n0 + n) * 2 + (lane >> 5)] = vd;
        }
    }
}

// ---------------- aggregation core, slot-parallel ----------------
// Fast path (deg<=64): lane = (cg=lane>>3 channel-group, slot=lane&7).
// One dwordx4 load covers 8 channels of one edge -> 8 edges per load instr.
// All shuffles convergent (R3 lesson: bpermute reads 0 from EXEC-off lanes).
// Returns the normalized aggregate for channel `lane`.
__device__ __forceinline__ float agg_core(const __hip_bfloat16* __restrict__ h_bf,
                                          const float* __restrict__ as_,
                                          const float* __restrict__ ad_,
                                          const int* __restrict__ col,
                                          int v, int rs, int re, int lane) {
    int head = lane >> 5;
    float adv0 = ad_[v * 2], adv1 = ad_[v * 2 + 1];
    int deg = re - rs;
    if (deg <= 64) {
        // prologue: lane j owns edge rs+j -> weights for both heads
        int sj = 0;
        float w0 = 0.f, w1 = 0.f;
        if (lane < deg) {
            sj = col[rs + lane];
            float2 av = *(const float2*)&as_[sj * 2];
            w0 = __expf(leaky(av.x + adv0));
            w1 = __expf(leaky(av.y + adv1));
        }
        float s0 = red64(w0), s1 = red64(w1);
        float rdh = 1.f / ((head ? s1 : s0) + 1e-16f);

        int slot = lane & 7;
        int cg   = lane >> 3;          // channel group: channels [cg*8, cg*8+8)
        bool hi  = cg >= 4;            // head of this lane's channel group
        float acc[8] = {0.f,0.f,0.f,0.f,0.f,0.f,0.f,0.f};
        int nit = (deg + 7) >> 3;

        auto body = [&](int g) {
            int j = g * 8 + slot;                       // edge idx within node (<64)
            int sA   = __shfl(sj, j, 64);               // 0 for j>=deg (safe addr)
            float wa = __shfl(w0, j, 64);
            float wb = __shfl(w1, j, 64);
            float w  = hi ? wb : wa;                    // 0 for j>=deg
            const uint4* p = (const uint4*)(h_bf + ((size_t)sA << 6) + (cg << 3));
            uint4 d = *p;
#pragma unroll
            for (int q = 0; q < 4; ++q) {
                unsigned int dw = (&d.x)[q];
                float lo = __uint_as_float(dw << 16);
                float hif = __uint_as_float(dw & 0xFFFF0000u);
                acc[2 * q]     = fmaf(w, lo,  acc[2 * q]);
                acc[2 * q + 1] = fmaf(w, hif, acc[2 * q + 1]);
            }
        };
        int g = 0;
        for (; g + 1 < nit; g += 2) { body(g); body(g + 1); }
        if (g < nit) body(g);

        // reduce over slots (lanes differing in bits 0..2)
#pragma unroll
        for (int m = 1; m <= 4; m <<= 1) {
#pragma unroll
            for (int q = 0; q < 8; ++q) acc[q] += __shfl_xor(acc[q], m, 64);
        }
        // lane's own cg == lane>>3, so channel `lane` is acc[lane&7]
        int k = lane & 7;
        float val = acc[0];
#pragma unroll
        for (int q = 1; q < 8; ++q) val = (k == q) ? acc[q] : val;
        return val * rdh;
    } else {
        // generic fallback (deg > 64): lane = channel
        float advh = head ? adv1 : adv0;
        float s0 = 0.f, s1 = 0.f;
        for (int e = rs + lane; e < re; e += 64) {
            int s = col[e];
            float2 av = *(const float2*)&as_[s * 2];
            s0 += __expf(leaky(av.x + adv0));
            s1 += __expf(leaky(av.y + adv1));
        }
        s0 = red64(s0); s1 = red64(s1);
        float rdh = 1.f / ((head ? s1 : s0) + 1e-16f);
        float a0 = 0.f;
        for (int e = rs; e < re; ++e) {
            int s = col[e];
            float w = __expf(leaky(as_[s * 2 + head] + advh));
            a0 = fmaf(w, __bfloat162float(h_bf[(size_t)s * 64 + lane]), a0);
        }
        return a0 * rdh;
    }
}

// ---------------- aggregation layer 1 (+bias, BN eval, ELU) -> x1 fp32 ----------------
__global__ __launch_bounds__(256) void agg1_kernel(const __hip_bfloat16* __restrict__ h_bf,
                                                   const float* __restrict__ as_,
                                                   const float* __restrict__ ad_,
                                                   const int* __restrict__ row_start,
                                                   const int* __restrict__ col,
                                                   const float* __restrict__ bias,
                                                   const float* __restrict__ bn_g,
                                                   const float* __restrict__ bn_b,
                                                   const float* __restrict__ bn_m,
                                                   const float* __restrict__ bn_v,
                                                   float* __restrict__ x1) {
    int t = threadIdx.x, wid = t >> 6, lane = t & 63;
    int v = blockIdx.x * 4 + wid;
    int rs = row_start[v], re = row_start[v + 1];
    float acc = agg_core(h_bf, as_, ad_, col, v, rs, re, lane);
    float r = acc + bias[lane];
    float scale = bn_g[lane] * rsqrtf(bn_v[lane] + BN_EPS);
    r = (r - bn_m[lane]) * scale + bn_b[lane];
    r = r > 0.f ? r : expm1f(r);   // ELU
    x1[(size_t)v * 64 + lane] = r;
}

// ---------------- aggregation layer 2 + JK max -> xj fp32 [N,64] ----------------
__global__ __launch_bounds__(256) void agg2_kernel(const __hip_bfloat16* __restrict__ h_bf,
                                                   const float* __restrict__ as_,
                                                   const float* __restrict__ ad_,
                                                   const int* __restrict__ row_start,
                                                   const int* __restrict__ col,
                                                   const float* __restrict__ bias,
                                                   const float* __restrict__ x1,
                                                   float* __restrict__ xj) {
    int t = threadIdx.x, wid = t >> 6, lane = t & 63;
    int v = blockIdx.x * 4 + wid;
    int rs = row_start[v], re = row_start[v + 1];
    float acc = agg_core(h_bf, as_, ad_, col, v, rs, re, lane);
    float x2 = acc + bias[lane];
    xj[(size_t)v * 64 + lane] = fmaxf(x1[(size_t)v * 64 + lane], x2);
}

// ---------------- final projection: out[N,40] = xj[N,64] @ Wf + bf ----------------
// block = 320 threads = 8 nodes x 40 outputs
__global__ __launch_bounds__(320) void proj_kernel(const float* __restrict__ xj,
                                                   const float* __restrict__ Wf,
                                                   const float* __restrict__ bf_,
                                                   const int* __restrict__ flag,
                                                   void* __restrict__ out) {
    __shared__ float Wt[40 * 68];    // transposed [o][c], stride 68
    __shared__ float xs[8 * 64];
    int t = threadIdx.x;
    for (int i = t; i < 2560; i += 320) {
        int c = i / 40, o = i % 40;
        Wt[o * 68 + c] = Wf[i];
    }
    int base = blockIdx.x * 8;
    for (int i = t; i < 512; i += 320) xs[i] = xj[(size_t)base * 64 + i];
    __syncthreads();

    int n = t / 40, o = t % 40;
    float po = 0.f;
#pragma unroll
    for (int k = 0; k < 16; ++k) {
        float4 xv = *(const float4*)&xs[n * 64 + k * 4];
        float4 wv = *(const float4*)&Wt[o * 68 + k * 4];
        po = fmaf(xv.x, wv.x, fmaf(xv.y, wv.y, fmaf(xv.z, wv.z, fmaf(xv.w, wv.w, po))));
    }
    float r = po + bf_[o];
    size_t idx = (size_t)(base + n) * 40 + o;
    if (*flag) ((float*)out)[idx] = r;
    else ((__hip_bfloat16*)out)[idx] = __float2bfloat16(r);
}

extern "C" void kernel_launch(void* const* d_in, const int* in_sizes, int n_in,
                              void* d_out, int out_size, void* d_ws, size_t ws_size,
                              hipStream_t stream) {
    (void)in_sizes; (void)n_in; (void)out_size; (void)ws_size;
    const void* node_feat = d_in[0];
    const int*  edge_idx  = (const int*)d_in[1];

    char* ws = (char*)d_ws;
    size_t off = 0;
    auto alloc = [&](size_t bytes) -> void* {
        void* p = ws + off;
        off += (bytes + 255) & ~(size_t)255;
        return p;
    };
    __hip_bfloat16* h_bf = (__hip_bfloat16*)alloc((size_t)N_NODES * 64 * 2);  // 12.8 MB
    float* x1  = (float*)alloc((size_t)N_NODES * 64 * 4);   // 25.6 MB
    float* xj  = (float*)alloc((size_t)N_NODES * 64 * 4);   // 25.6 MB
    float* as_ = (float*)alloc((size_t)N_NODES * 2 * 4);
    float* ad_ = (float*)alloc((size_t)N_NODES * 2 * 4);
    int* deg       = (int*)alloc((size_t)N_NODES * 4);
    int* row_start = (int*)alloc((size_t)(N_NODES + 1) * 4);
    int* cursor    = (int*)alloc((size_t)N_NODES * 4);
    int* col       = (int*)alloc((size_t)ETOT * 4);         // 6.8 MB
    int* bsum      = (int*)alloc((size_t)NB_SCAN * 4);
    int* boff      = (int*)alloc((size_t)NB_SCAN * 4);
    float* prm     = (float*)alloc((size_t)P_TOT * 4);
    int* flag      = (int*)alloc(256);

    detect_kernel<<<1, 64, 0, stream>>>((const unsigned short*)node_feat, flag);
    CvtArgs ca;
    const int lens[14] = {8192, 64, 64, 64, 64, 64, 64, 64, 4096, 64, 64, 64, 2560, 40};
    for (int i = 0; i < 14; ++i) { ca.ptr[i] = d_in[i + 2]; ca.len[i] = lens[i]; }
    cvt_params_kernel<<<(P_TOT + 255) / 256, 256, 0, stream>>>(ca, flag, prm);

    const int eb = (ETOT + 255) / 256;

    hipMemsetAsync(deg, 0, (size_t)N_NODES * 4, stream);
    hist_kernel<<<eb, 256, 0, stream>>>(edge_idx, deg);
    scanA_kernel<<<NB_SCAN, 256, 0, stream>>>(deg, bsum);
    scanB_kernel<<<1, 512, 0, stream>>>(bsum, boff, row_start);
    scanC_kernel<<<NB_SCAN, 256, 0, stream>>>(deg, boff, row_start, cursor);
    scatter_kernel<<<eb, 256, 0, stream>>>(edge_idx, cursor, col);

    gemm1_kernel<<<N_NODES / 16, 256, 0, stream>>>(node_feat, prm + P_W1,
                                                   prm + P_AS1, prm + P_AD1,
                                                   flag, h_bf, as_, ad_);
    agg1_kernel<<<N_NODES / 4, 256, 0, stream>>>(h_bf, as_, ad_, row_start, col,
                                                 prm + P_B1, prm + P_BNG, prm + P_BNB,
                                                 prm + P_BNM, prm + P_BNV, x1);
    gemm2_kernel<<<N_NODES / 16, 256, 0, stream>>>(x1, prm + P_W2,
                                                   prm + P_AS2, prm + P_AD2,
                                                   h_bf, as_, ad_);
    agg2_kernel<<<N_NODES / 4, 256, 0, stream>>>(h_bf, as_, ad_, row_start, col,
                                                 prm + P_B2, x1, xj);
    proj_kernel<<<N_NODES / 8, 320, 0, stream>>>(xj, prm + P_WF, prm + P_BF,
                                                 flag, d_out);
}

// Round 6
// 484.607 us; speedup vs baseline: 2.2317x; 1.4501x over previous
//
#include <hip/hip_runtime.h>
#include <hip/hip_bf16.h>

#define N_NODES 100000
#define E_EDGES 1600000
#define ETOT    1700000   // E + N self-loops
#define NB_SCAN 391       // ceil(N/256)
#define F_IN    128
#define HC      64
#define OUT_C   40
#define NEG_SLOPE 0.2f
#define BN_EPS  1e-5f

// fp32 param block layout (element offsets)
#define P_W1   0
#define P_AS1  8192
#define P_AD1  8256
#define P_B1   8320
#define P_BNG  8384
#define P_BNB  8448
#define P_BNM  8512
#define P_BNV  8576
#define P_W2   8640
#define P_AS2  12736
#define P_AD2  12800
#define P_B2   12864
#define P_WF   12928
#define P_BF   15488
#define P_TOT  15528

typedef __attribute__((ext_vector_type(8))) short short8;
typedef __attribute__((ext_vector_type(4))) float floatx4;

__device__ __forceinline__ unsigned short f2bf(float f) {   // RNE fp32->bf16
    unsigned int u = __float_as_uint(f);
    unsigned int r = u + 0x7FFFu + ((u >> 16) & 1u);
    return (unsigned short)(r >> 16);
}

// ---------------- dtype detection ----------------
__global__ __launch_bounds__(64) void detect_kernel(const unsigned short* __restrict__ x,
                                                    int* __restrict__ flag) {
    int t = threadIdx.x;
    bool huge = false;
#pragma unroll
    for (int i = 0; i < 4; ++i) {
        unsigned short u = x[(t * 4 + i) * 2];
        float v = __uint_as_float(((unsigned int)u) << 16);
        if (!(fabsf(v) < 1e4f)) huge = true;
    }
    unsigned long long b = __ballot(huge);
    if (t == 0) *flag = (b != 0ull) ? 1 : 0;             // 1 => fp32 tensors
}

// ---------------- small-param conversion to fp32 ----------------
struct CvtArgs { const void* ptr[14]; int len[14]; };

__global__ __launch_bounds__(256) void cvt_params_kernel(CvtArgs a,
                                                         const int* __restrict__ flag,
                                                         float* __restrict__ dst) {
    int f = *flag;
    int i = blockIdx.x * 256 + threadIdx.x;
    if (i >= P_TOT) return;
    int k = 0, off = 0;
    while (i >= off + a.len[k]) { off += a.len[k]; ++k; }
    int j = i - off;
    float v = f ? ((const float*)a.ptr[k])[j]
                : __bfloat162float(((const __hip_bfloat16*)a.ptr[k])[j]);
    dst[i] = v;
}

// ---------------- W1/W2 -> bf16 MFMA B-fragment order ----------------
// fragW[t][q][l][j]: B[n = t*16 + (l&15)][k = q*32 + (l>>4)*8 + j]
__global__ __launch_bounds__(256) void build_frags_kernel(const float* __restrict__ prm,
                                                          unsigned short* __restrict__ fw1,
                                                          unsigned short* __restrict__ fw2) {
    int i = blockIdx.x * 256 + threadIdx.x;
    if (i < 8192) {
        int j = i & 7, l = (i >> 3) & 63, q = (i >> 9) & 3, t = i >> 11;
        int k = q * 32 + (l >> 4) * 8 + j;
        int n = t * 16 + (l & 15);
        fw1[i] = f2bf(prm[P_W1 + k * 64 + n]);
    } else if (i < 12288) {
        int f = i - 8192;
        int j = f & 7, l = (f >> 3) & 63, q = (f >> 9) & 1, t = f >> 10;
        int k = q * 32 + (l >> 4) * 8 + j;
        int n = t * 16 + (l & 15);
        fw2[f] = f2bf(prm[P_W2 + k * 64 + n]);
    }
}

// ---------------- CSR build ----------------
__global__ __launch_bounds__(256) void hist_kernel(const int* __restrict__ ei,
                                                   int* __restrict__ deg) {
    int i = blockIdx.x * 256 + threadIdx.x;
    if (i >= ETOT) return;
    int d = (i < E_EDGES) ? ei[E_EDGES + i] : (i - E_EDGES);
    atomicAdd(&deg[d], 1);
}

__global__ __launch_bounds__(256) void scanA_kernel(const int* __restrict__ deg,
                                                    int* __restrict__ bsum) {
    __shared__ int sm[256];
    int t = threadIdx.x;
    int i = blockIdx.x * 256 + t;
    sm[t] = (i < N_NODES) ? deg[i] : 0;
    __syncthreads();
    for (int off = 128; off > 0; off >>= 1) {
        if (t < off) sm[t] += sm[t + off];
        __syncthreads();
    }
    if (t == 0) bsum[blockIdx.x] = sm[0];
}

__global__ __launch_bounds__(512) void scanB_kernel(const int* __restrict__ bsum,
                                                    int* __restrict__ boff,
                                                    int* __restrict__ row_start) {
    __shared__ int sm[512];
    int t = threadIdx.x;
    int v = (t < NB_SCAN) ? bsum[t] : 0;
    sm[t] = v;
    __syncthreads();
    for (int off = 1; off < 512; off <<= 1) {
        int o = (t >= off) ? sm[t - off] : 0;
        __syncthreads();
        sm[t] += o;
        __syncthreads();
    }
    if (t < NB_SCAN) boff[t] = sm[t] - v;
    if (t == NB_SCAN - 1) row_start[N_NODES] = sm[t];
}

__global__ __launch_bounds__(256) void scanC_kernel(const int* __restrict__ deg,
                                                    const int* __restrict__ boff,
                                                    int* __restrict__ row_start,
                                                    int* __restrict__ cursor) {
    __shared__ int sm[256];
    int t = threadIdx.x;
    int i = blockIdx.x * 256 + t;
    int v = (i < N_NODES) ? deg[i] : 0;
    sm[t] = v;
    __syncthreads();
    for (int off = 1; off < 256; off <<= 1) {
        int o = (t >= off) ? sm[t - off] : 0;
        __syncthreads();
        sm[t] += o;
        __syncthreads();
    }
    if (i < N_NODES) {
        int excl = sm[t] - v + boff[blockIdx.x];
        row_start[i] = excl;
        cursor[i]    = excl;
    }
}

__global__ __launch_bounds__(256) void scatter_kernel(const int* __restrict__ ei,
                                                      int* __restrict__ cursor,
                                                      int* __restrict__ col) {
    int i = blockIdx.x * 256 + threadIdx.x;
    if (i >= ETOT) return;
    int s, d;
    if (i < E_EDGES) { s = ei[i]; d = ei[E_EDGES + i]; }
    else             { s = d = i - E_EDGES; }
    int pos = atomicAdd(&cursor[d], 1);
    col[pos] = s;
}

__device__ __forceinline__ float leaky(float v) { return v > 0.f ? v : NEG_SLOPE * v; }

__device__ __forceinline__ float red64(float v) {
#pragma unroll
    for (int off = 32; off > 0; off >>= 1) v += __shfl_xor(v, off, 64);
    return v;
}
// reduce within 16-lane group (bits 0..3)
__device__ __forceinline__ float red16(float v) {
#pragma unroll
    for (int off = 8; off > 0; off >>= 1) v += __shfl_xor(v, off, 64);
    return v;
}

// ---------------- MFMA GEMM 1: h_bf[N,64] = x[N,128] @ W1, + fused alpha ----------------
// block = 128 threads (2 waves), 32 nodes/block, grid = N/32 = 3125.
// LDS holds the x-tile in A-fragment order; W1 is pre-fragmented in global (fw1).
__global__ __launch_bounds__(128) void gemm1_kernel(const void* __restrict__ x,
                                                    const unsigned short* __restrict__ fw1,
                                                    const float* __restrict__ prm,
                                                    const int* __restrict__ flag,
                                                    unsigned short* __restrict__ h_bf,
                                                    float* __restrict__ as_,
                                                    float* __restrict__ ad_) {
    __shared__ short lx[2 * 4 * 64 * 8];   // [w][q][l][8] = 8 KB
    int t = threadIdx.x;
    int f = *flag;
    int base = blockIdx.x * 32;

    // stage 32 x-rows (128 k each) into A-frag order; 512 chunks of 8 elems
#pragma unroll
    for (int i = 0; i < 4; ++i) {
        int cid = i * 128 + t;
        int m = cid >> 4, c = cid & 15;
        int q = c >> 2, g = c & 3;
        int loff = (((m >> 4) * 4 + q) * 64 + g * 16 + (m & 15)) * 8;
        short8 s;
        if (f) {
            const float4* p = (const float4*)((const float*)x + ((size_t)(base + m) << 7) + (c << 3));
            float4 u0 = p[0], u1 = p[1];
            s[0] = (short)f2bf(u0.x); s[1] = (short)f2bf(u0.y);
            s[2] = (short)f2bf(u0.z); s[3] = (short)f2bf(u0.w);
            s[4] = (short)f2bf(u1.x); s[5] = (short)f2bf(u1.y);
            s[6] = (short)f2bf(u1.z); s[7] = (short)f2bf(u1.w);
        } else {
            s = *(const short8*)((const unsigned short*)x + ((size_t)(base + m) << 7) + (c << 3));
        }
        *(short8*)&lx[loff] = s;
    }
    __syncthreads();

    int w = t >> 6, lane = t & 63;
    short8 a[4];
#pragma unroll
    for (int q = 0; q < 4; ++q) a[q] = *(short8*)&lx[((w * 4 + q) * 64 + lane) * 8];

    const short8* bw = (const short8*)fw1;
    floatx4 acc[4];
#pragma unroll
    for (int tt = 0; tt < 4; ++tt) acc[tt] = (floatx4){0.f, 0.f, 0.f, 0.f};
#pragma unroll
    for (int tt = 0; tt < 4; ++tt) {
#pragma unroll
        for (int q = 0; q < 4; ++q) {
            short8 b = bw[(tt * 4 + q) * 64 + lane];
            acc[tt] = __builtin_amdgcn_mfma_f32_16x16x32_bf16(a[q], b, acc[tt], 0, 0, 0);
        }
    }

    // D layout: lane holds D[row=(lane>>4)*4+r][col=lane&15]; node = base+w*16+row, ch = tt*16+col
    int cl = lane & 15, grp = lane >> 4;
#pragma unroll
    for (int tt = 0; tt < 4; ++tt) {
#pragma unroll
        for (int r = 0; r < 4; ++r) {
            int node = base + w * 16 + grp * 4 + r;
            h_bf[(size_t)node * 64 + tt * 16 + cl] = f2bf(acc[tt][r]);
        }
    }

    // fused alpha: as[n,h] = sum_c h[n,h,c]*a_s[h,c]
    float as0 = prm[P_AS1 + 0  + cl], as1 = prm[P_AS1 + 16 + cl],
          as2 = prm[P_AS1 + 32 + cl], as3 = prm[P_AS1 + 48 + cl];
    float ad0 = prm[P_AD1 + 0  + cl], ad1 = prm[P_AD1 + 16 + cl],
          ad2 = prm[P_AD1 + 32 + cl], ad3 = prm[P_AD1 + 48 + cl];
#pragma unroll
    for (int r = 0; r < 4; ++r) {
        float sh0 = red16(acc[0][r] * as0 + acc[1][r] * as1);
        float sh1 = red16(acc[2][r] * as2 + acc[3][r] * as3);
        float dh0 = red16(acc[0][r] * ad0 + acc[1][r] * ad1);
        float dh1 = red16(acc[2][r] * ad2 + acc[3][r] * ad3);
        if (cl == 0) {
            int node = base + w * 16 + grp * 4 + r;
            as_[node * 2] = sh0;  as_[node * 2 + 1] = sh1;
            ad_[node * 2] = dh0;  ad_[node * 2 + 1] = dh1;
        }
    }
}

// ---------------- MFMA GEMM 2: h_bf = x1_bf[N,64] @ W2, + fused alpha ----------------
__global__ __launch_bounds__(128) void gemm2_kernel(const unsigned short* __restrict__ x1_bf,
                                                    const unsigned short* __restrict__ fw2,
                                                    const float* __restrict__ prm,
                                                    unsigned short* __restrict__ h_bf,
                                                    float* __restrict__ as_,
                                                    float* __restrict__ ad_) {
    __shared__ short lx[2 * 2 * 64 * 8];   // 4 KB
    int t = threadIdx.x;
    int base = blockIdx.x * 32;

    // 256 chunks of 8 elems
#pragma unroll
    for (int i = 0; i < 2; ++i) {
        int cid = i * 128 + t;
        int m = cid >> 3, c = cid & 7;
        int q = c >> 2, g = c & 3;
        int loff = (((m >> 4) * 2 + q) * 64 + g * 16 + (m & 15)) * 8;
        short8 s = *(const short8*)(x1_bf + ((size_t)(base + m) << 6) + (c << 3));
        *(short8*)&lx[loff] = s;
    }
    __syncthreads();

    int w = t >> 6, lane = t & 63;
    short8 a[2];
#pragma unroll
    for (int q = 0; q < 2; ++q) a[q] = *(short8*)&lx[((w * 2 + q) * 64 + lane) * 8];

    const short8* bw = (const short8*)fw2;
    floatx4 acc[4];
#pragma unroll
    for (int tt = 0; tt < 4; ++tt) acc[tt] = (floatx4){0.f, 0.f, 0.f, 0.f};
#pragma unroll
    for (int tt = 0; tt < 4; ++tt) {
#pragma unroll
        for (int q = 0; q < 2; ++q) {
            short8 b = bw[(tt * 2 + q) * 64 + lane];
            acc[tt] = __builtin_amdgcn_mfma_f32_16x16x32_bf16(a[q], b, acc[tt], 0, 0, 0);
        }
    }

    int cl = lane & 15, grp = lane >> 4;
#pragma unroll
    for (int tt = 0; tt < 4; ++tt) {
#pragma unroll
        for (int r = 0; r < 4; ++r) {
            int node = base + w * 16 + grp * 4 + r;
            h_bf[(size_t)node * 64 + tt * 16 + cl] = f2bf(acc[tt][r]);
        }
    }

    float as0 = prm[P_AS2 + 0  + cl], as1 = prm[P_AS2 + 16 + cl],
          as2 = prm[P_AS2 + 32 + cl], as3 = prm[P_AS2 + 48 + cl];
    float ad0 = prm[P_AD2 + 0  + cl], ad1 = prm[P_AD2 + 16 + cl],
          ad2 = prm[P_AD2 + 32 + cl], ad3 = prm[P_AD2 + 48 + cl];
#pragma unroll
    for (int r = 0; r < 4; ++r) {
        float sh0 = red16(acc[0][r] * as0 + acc[1][r] * as1);
        float sh1 = red16(acc[2][r] * as2 + acc[3][r] * as3);
        float dh0 = red16(acc[0][r] * ad0 + acc[1][r] * ad1);
        float dh1 = red16(acc[2][r] * ad2 + acc[3][r] * ad3);
        if (cl == 0) {
            int node = base + w * 16 + grp * 4 + r;
            as_[node * 2] = sh0;  as_[node * 2 + 1] = sh1;
            ad_[node * 2] = dh0;  ad_[node * 2 + 1] = dh1;
        }
    }
}

// ---------------- aggregation core, slot-parallel (R5 design, unchanged) ----------------
__device__ __forceinline__ float agg_core(const unsigned short* __restrict__ h_bf,
                                          const float* __restrict__ as_,
                                          const float* __restrict__ ad_,
                                          const int* __restrict__ col,
                                          int v, int rs, int re, int lane) {
    int head = lane >> 5;
    float adv0 = ad_[v * 2], adv1 = ad_[v * 2 + 1];
    int deg = re - rs;
    if (deg <= 64) {
        int sj = 0;
        float w0 = 0.f, w1 = 0.f;
        if (lane < deg) {
            sj = col[rs + lane];
            float2 av = *(const float2*)&as_[sj * 2];
            w0 = __expf(leaky(av.x + adv0));
            w1 = __expf(leaky(av.y + adv1));
        }
        float s0 = red64(w0), s1 = red64(w1);
        float rdh = 1.f / ((head ? s1 : s0) + 1e-16f);

        int slot = lane & 7;
        int cg   = lane >> 3;
        bool hi  = cg >= 4;
        float acc[8] = {0.f,0.f,0.f,0.f,0.f,0.f,0.f,0.f};
        int nit = (deg + 7) >> 3;

        auto body = [&](int g) {
            int j = g * 8 + slot;
            int sA   = __shfl(sj, j, 64);
            float wa = __shfl(w0, j, 64);
            float wb = __shfl(w1, j, 64);
            float w  = hi ? wb : wa;
            const uint4* p = (const uint4*)(h_bf + ((size_t)sA << 6) + (cg << 3));
            uint4 d = *p;
#pragma unroll
            for (int q = 0; q < 4; ++q) {
                unsigned int dw = (&d.x)[q];
                float lo  = __uint_as_float(dw << 16);
                float hif = __uint_as_float(dw & 0xFFFF0000u);
                acc[2 * q]     = fmaf(w, lo,  acc[2 * q]);
                acc[2 * q + 1] = fmaf(w, hif, acc[2 * q + 1]);
            }
        };
        int g = 0;
        for (; g + 1 < nit; g += 2) { body(g); body(g + 1); }
        if (g < nit) body(g);

#pragma unroll
        for (int m = 1; m <= 4; m <<= 1) {
#pragma unroll
            for (int q = 0; q < 8; ++q) acc[q] += __shfl_xor(acc[q], m, 64);
        }
        int k = lane & 7;
        float val = acc[0];
#pragma unroll
        for (int q = 1; q < 8; ++q) val = (k == q) ? acc[q] : val;
        return val * rdh;
    } else {
        float advh = head ? adv1 : adv0;
        float s0 = 0.f, s1 = 0.f;
        for (int e = rs + lane; e < re; e += 64) {
            int s = col[e];
            float2 av = *(const float2*)&as_[s * 2];
            s0 += __expf(leaky(av.x + adv0));
            s1 += __expf(leaky(av.y + adv1));
        }
        s0 = red64(s0); s1 = red64(s1);
        float rdh = 1.f / ((head ? s1 : s0) + 1e-16f);
        float a0 = 0.f;
        for (int e = rs; e < re; ++e) {
            int s = col[e];
            float w = __expf(leaky(as_[s * 2 + head] + advh));
            unsigned short u = h_bf[(size_t)s * 64 + lane];
            a0 = fmaf(w, __uint_as_float(((unsigned int)u) << 16), a0);
        }
        return a0 * rdh;
    }
}

// ---------------- aggregation layer 1 (+bias, BN eval, ELU) -> x1_bf ----------------
__global__ __launch_bounds__(256) void agg1_kernel(const unsigned short* __restrict__ h_bf,
                                                   const float* __restrict__ as_,
                                                   const float* __restrict__ ad_,
                                                   const int* __restrict__ row_start,
                                                   const int* __restrict__ col,
                                                   const float* __restrict__ bias,
                                                   const float* __restrict__ bn_g,
                                                   const float* __restrict__ bn_b,
                                                   const float* __restrict__ bn_m,
                                                   const float* __restrict__ bn_v,
                                                   unsigned short* __restrict__ x1_bf) {
    int t = threadIdx.x, wid = t >> 6, lane = t & 63;
    int v = blockIdx.x * 4 + wid;
    int rs = row_start[v], re = row_start[v + 1];
    float acc = agg_core(h_bf, as_, ad_, col, v, rs, re, lane);
    float r = acc + bias[lane];
    float scale = bn_g[lane] * rsqrtf(bn_v[lane] + BN_EPS);
    r = (r - bn_m[lane]) * scale + bn_b[lane];
    r = r > 0.f ? r : expm1f(r);   // ELU
    x1_bf[(size_t)v * 64 + lane] = f2bf(r);
}

// ---------------- aggregation layer 2 + JK max -> xj fp32 ----------------
__global__ __launch_bounds__(256) void agg2_kernel(const unsigned short* __restrict__ h_bf,
                                                   const float* __restrict__ as_,
                                                   const float* __restrict__ ad_,
                                                   const int* __restrict__ row_start,
                                                   const int* __restrict__ col,
                                                   const float* __restrict__ bias,
                                                   const unsigned short* __restrict__ x1_bf,
                                                   float* __restrict__ xj) {
    int t = threadIdx.x, wid = t >> 6, lane = t & 63;
    int v = blockIdx.x * 4 + wid;
    int rs = row_start[v], re = row_start[v + 1];
    float acc = agg_core(h_bf, as_, ad_, col, v, rs, re, lane);
    float x2 = acc + bias[lane];
    unsigned short u = x1_bf[(size_t)v * 64 + lane];
    float x1v = __uint_as_float(((unsigned int)u) << 16);
    xj[(size_t)v * 64 + lane] = fmaxf(x1v, x2);
}

// ---------------- final projection: out[N,40] = xj[N,64] @ Wf + bf ----------------
__global__ __launch_bounds__(320) void proj_kernel(const float* __restrict__ xj,
                                                   const float* __restrict__ Wf,
                                                   const float* __restrict__ bf_,
                                                   const int* __restrict__ flag,
                                                   void* __restrict__ out) {
    __shared__ float Wt[40 * 68];
    __shared__ float xs[8 * 64];
    int t = threadIdx.x;
    for (int i = t; i < 2560; i += 320) {
        int c = i / 40, o = i % 40;
        Wt[o * 68 + c] = Wf[i];
    }
    int base = blockIdx.x * 8;
    for (int i = t; i < 512; i += 320) xs[i] = xj[(size_t)base * 64 + i];
    __syncthreads();

    int n = t / 40, o = t % 40;
    float po = 0.f;
#pragma unroll
    for (int k = 0; k < 16; ++k) {
        float4 xv = *(const float4*)&xs[n * 64 + k * 4];
        float4 wv = *(const float4*)&Wt[o * 68 + k * 4];
        po = fmaf(xv.x, wv.x, fmaf(xv.y, wv.y, fmaf(xv.z, wv.z, fmaf(xv.w, wv.w, po))));
    }
    float r = po + bf_[o];
    size_t idx = (size_t)(base + n) * 40 + o;
    if (*flag) ((float*)out)[idx] = r;
    else ((__hip_bfloat16*)out)[idx] = __float2bfloat16(r);
}

extern "C" void kernel_launch(void* const* d_in, const int* in_sizes, int n_in,
                              void* d_out, int out_size, void* d_ws, size_t ws_size,
                              hipStream_t stream) {
    (void)in_sizes; (void)n_in; (void)out_size; (void)ws_size;
    const void* node_feat = d_in[0];
    const int*  edge_idx  = (const int*)d_in[1];

    char* ws = (char*)d_ws;
    size_t off = 0;
    auto alloc = [&](size_t bytes) -> void* {
        void* p = ws + off;
        off += (bytes + 255) & ~(size_t)255;
        return p;
    };
    unsigned short* h_bf  = (unsigned short*)alloc((size_t)N_NODES * 64 * 2);  // 12.8 MB
    unsigned short* x1_bf = (unsigned short*)alloc((size_t)N_NODES * 64 * 2);  // 12.8 MB
    float* xj  = (float*)alloc((size_t)N_NODES * 64 * 4);   // 25.6 MB
    float* as_ = (float*)alloc((size_t)N_NODES * 2 * 4);
    float* ad_ = (float*)alloc((size_t)N_NODES * 2 * 4);
    int* deg       = (int*)alloc((size_t)N_NODES * 4);
    int* row_start = (int*)alloc((size_t)(N_NODES + 1) * 4);
    int* cursor    = (int*)alloc((size_t)N_NODES * 4);
    int* col       = (int*)alloc((size_t)ETOT * 4);         // 6.8 MB
    int* bsum      = (int*)alloc((size_t)NB_SCAN * 4);
    int* boff      = (int*)alloc((size_t)NB_SCAN * 4);
    float* prm     = (float*)alloc((size_t)P_TOT * 4);
    unsigned short* fw1 = (unsigned short*)alloc(8192 * 2);
    unsigned short* fw2 = (unsigned short*)alloc(4096 * 2);
    int* flag      = (int*)alloc(256);

    detect_kernel<<<1, 64, 0, stream>>>((const unsigned short*)node_feat, flag);
    CvtArgs ca;
    const int lens[14] = {8192, 64, 64, 64, 64, 64, 64, 64, 4096, 64, 64, 64, 2560, 40};
    for (int i = 0; i < 14; ++i) { ca.ptr[i] = d_in[i + 2]; ca.len[i] = lens[i]; }
    cvt_params_kernel<<<(P_TOT + 255) / 256, 256, 0, stream>>>(ca, flag, prm);
    build_frags_kernel<<<48, 256, 0, stream>>>(prm, fw1, fw2);

    const int eb = (ETOT + 255) / 256;

    hipMemsetAsync(deg, 0, (size_t)N_NODES * 4, stream);
    hist_kernel<<<eb, 256, 0, stream>>>(edge_idx, deg);
    scanA_kernel<<<NB_SCAN, 256, 0, stream>>>(deg, bsum);
    scanB_kernel<<<1, 512, 0, stream>>>(bsum, boff, row_start);
    scanC_kernel<<<NB_SCAN, 256, 0, stream>>>(deg, boff, row_start, cursor);
    scatter_kernel<<<eb, 256, 0, stream>>>(edge_idx, cursor, col);

    gemm1_kernel<<<N_NODES / 32, 128, 0, stream>>>(node_feat, fw1, prm, flag,
                                                   h_bf, as_, ad_);
    agg1_kernel<<<N_NODES / 4, 256, 0, stream>>>(h_bf, as_, ad_, row_start, col,
                                                 prm + P_B1, prm + P_BNG, prm + P_BNB,
                                                 prm + P_BNM, prm + P_BNV, x1_bf);
    gemm2_kernel<<<N_NODES / 32, 128, 0, stream>>>(x1_bf, fw2, prm,
                                                   h_bf, as_, ad_);
    agg2_kernel<<<N_NODES / 4, 256, 0, stream>>>(h_bf, as_, ad_, row_start, col,
                                                 prm + P_B2, x1_bf, xj);
    proj_kernel<<<N_NODES / 8, 320, 0, stream>>>(xj, prm + P_WF, prm + P_BF,
                                                 flag, d_out);
}

// Round 7
// 447.092 us; speedup vs baseline: 2.4190x; 1.0839x over previous
//
#include <hip/hip_runtime.h>
#include <hip/hip_bf16.h>

#define N_NODES 100000
#define E_EDGES 1600000
#define ETOT    1700000   // E + N self-loops
#define NB_SCAN 391       // ceil(N/256)
#define F_IN    128
#define HC      64
#define OUT_C   40
#define NEG_SLOPE 0.2f
#define BN_EPS  1e-5f

// destination banding for CSR build (write-locality + XCD affinity)
#define BAND_SZ 12500     // nodes per band; 8 bands cover N exactly
#define SLICE_E 8192      // edges per block-slice
#define N_SLICE 196       // ceil(E_EDGES / SLICE_E)

// fp32 param block layout (element offsets)
#define P_W1   0
#define P_AS1  8192
#define P_AD1  8256
#define P_B1   8320
#define P_BNG  8384
#define P_BNB  8448
#define P_BNM  8512
#define P_BNV  8576
#define P_W2   8640
#define P_AS2  12736
#define P_AD2  12800
#define P_B2   12864
#define P_WF   12928
#define P_BF   15488
#define P_TOT  15528

typedef __attribute__((ext_vector_type(8))) short short8;
typedef __attribute__((ext_vector_type(4))) float floatx4;

__device__ __forceinline__ unsigned short f2bf(float f) {   // RNE fp32->bf16
    unsigned int u = __float_as_uint(f);
    unsigned int r = u + 0x7FFFu + ((u >> 16) & 1u);
    return (unsigned short)(r >> 16);
}

// ---------------- dtype detection ----------------
__global__ __launch_bounds__(64) void detect_kernel(const unsigned short* __restrict__ x,
                                                    int* __restrict__ flag) {
    int t = threadIdx.x;
    bool huge = false;
#pragma unroll
    for (int i = 0; i < 4; ++i) {
        unsigned short u = x[(t * 4 + i) * 2];
        float v = __uint_as_float(((unsigned int)u) << 16);
        if (!(fabsf(v) < 1e4f)) huge = true;
    }
    unsigned long long b = __ballot(huge);
    if (t == 0) *flag = (b != 0ull) ? 1 : 0;             // 1 => fp32 tensors
}

// ---------------- small-param conversion to fp32 ----------------
struct CvtArgs { const void* ptr[14]; int len[14]; };

__global__ __launch_bounds__(256) void cvt_params_kernel(CvtArgs a,
                                                         const int* __restrict__ flag,
                                                         float* __restrict__ dst) {
    int f = *flag;
    int i = blockIdx.x * 256 + threadIdx.x;
    if (i >= P_TOT) return;
    int k = 0, off = 0;
    while (i >= off + a.len[k]) { off += a.len[k]; ++k; }
    int j = i - off;
    float v = f ? ((const float*)a.ptr[k])[j]
                : __bfloat162float(((const __hip_bfloat16*)a.ptr[k])[j]);
    dst[i] = v;
}

// ---------------- W1/W2 -> bf16 MFMA B-fragment order ----------------
__global__ __launch_bounds__(256) void build_frags_kernel(const float* __restrict__ prm,
                                                          unsigned short* __restrict__ fw1,
                                                          unsigned short* __restrict__ fw2) {
    int i = blockIdx.x * 256 + threadIdx.x;
    if (i < 8192) {
        int j = i & 7, l = (i >> 3) & 63, q = (i >> 9) & 3, t = i >> 11;
        int k = q * 32 + (l >> 4) * 8 + j;
        int n = t * 16 + (l & 15);
        fw1[i] = f2bf(prm[P_W1 + k * 64 + n]);
    } else if (i < 12288) {
        int f = i - 8192;
        int j = f & 7, l = (f >> 3) & 63, q = (f >> 9) & 1, t = f >> 10;
        int k = q * 32 + (l >> 4) * 8 + j;
        int n = t * 16 + (l & 15);
        fw2[f] = f2bf(prm[P_W2 + k * 64 + n]);
    }
}

// ---------------- CSR build: banded histogram over REAL edges ----------------
// band = blockIdx & 7 -> same-band blocks land on one XCD (round-robin
// heuristic); each band's deg window (50 KB) stays L2-local.
__global__ __launch_bounds__(256) void hist_kernel(const int* __restrict__ ei,
                                                   int* __restrict__ deg) {
    int band  = blockIdx.x & 7;
    int slice = blockIdx.x >> 3;
    int blo = band * BAND_SZ, bhi = blo + BAND_SZ;
    const int4* dst4 = (const int4*)(ei + E_EDGES);
    int base4 = slice * (SLICE_E / 4);
#pragma unroll
    for (int it = 0; it < 8; ++it) {
        int i4 = base4 + it * 256 + threadIdx.x;
        if (i4 < E_EDGES / 4) {
            int4 d4 = dst4[i4];
#pragma unroll
            for (int c = 0; c < 4; ++c) {
                int d = (&d4.x)[c];
                if (d >= blo && d < bhi) atomicAdd(&deg[d], 1);
            }
        }
    }
}

// parallel scan; degree counted as deg[i]+1 (self-loop folded in here)
__global__ __launch_bounds__(256) void scanA_kernel(const int* __restrict__ deg,
                                                    int* __restrict__ bsum) {
    __shared__ int sm[256];
    int t = threadIdx.x;
    int i = blockIdx.x * 256 + t;
    sm[t] = (i < N_NODES) ? deg[i] + 1 : 0;
    __syncthreads();
    for (int off = 128; off > 0; off >>= 1) {
        if (t < off) sm[t] += sm[t + off];
        __syncthreads();
    }
    if (t == 0) bsum[blockIdx.x] = sm[0];
}

__global__ __launch_bounds__(512) void scanB_kernel(const int* __restrict__ bsum,
                                                    int* __restrict__ boff,
                                                    int* __restrict__ row_start) {
    __shared__ int sm[512];
    int t = threadIdx.x;
    int v = (t < NB_SCAN) ? bsum[t] : 0;
    sm[t] = v;
    __syncthreads();
    for (int off = 1; off < 512; off <<= 1) {
        int o = (t >= off) ? sm[t - off] : 0;
        __syncthreads();
        sm[t] += o;
        __syncthreads();
    }
    if (t < NB_SCAN) boff[t] = sm[t] - v;
    if (t == NB_SCAN - 1) row_start[N_NODES] = sm[t];   // == ETOT
}

// writes row_start, seeds cursor past the self-loop slot, and writes the
// self-loop col entry (coalesced-ish: excl is monotone in i)
__global__ __launch_bounds__(256) void scanC_kernel(const int* __restrict__ deg,
                                                    const int* __restrict__ boff,
                                                    int* __restrict__ row_start,
                                                    int* __restrict__ cursor,
                                                    int* __restrict__ col) {
    __shared__ int sm[256];
    int t = threadIdx.x;
    int i = blockIdx.x * 256 + t;
    int v = (i < N_NODES) ? deg[i] + 1 : 0;
    sm[t] = v;
    __syncthreads();
    for (int off = 1; off < 256; off <<= 1) {
        int o = (t >= off) ? sm[t - off] : 0;
        __syncthreads();
        sm[t] += o;
        __syncthreads();
    }
    if (i < N_NODES) {
        int excl = sm[t] - v + boff[blockIdx.x];
        row_start[i] = excl;
        cursor[i]    = excl + 1;   // slot 0 = self-loop
        col[excl]    = i;
    }
}

// ---------------- banded scatter of REAL edges ----------------
// writes confined to this band's 0.85 MB col window (+50 KB cursor) -> stays
// in one XCD's L2 instead of 16x-amplified random HBM evictions (R6: 108 MB).
__global__ __launch_bounds__(256) void scatter_kernel(const int* __restrict__ ei,
                                                      int* __restrict__ cursor,
                                                      int* __restrict__ col) {
    int band  = blockIdx.x & 7;
    int slice = blockIdx.x >> 3;
    int blo = band * BAND_SZ, bhi = blo + BAND_SZ;
    const int4* dst4 = (const int4*)(ei + E_EDGES);
    int base4 = slice * (SLICE_E / 4);
#pragma unroll
    for (int it = 0; it < 8; ++it) {
        int i4 = base4 + it * 256 + threadIdx.x;
        if (i4 < E_EDGES / 4) {
            int4 d4 = dst4[i4];
#pragma unroll
            for (int c = 0; c < 4; ++c) {
                int d = (&d4.x)[c];
                if (d >= blo && d < bhi) {
                    int s = ei[i4 * 4 + c];
                    int pos = atomicAdd(&cursor[d], 1);
                    col[pos] = s;
                }
            }
        }
    }
}

__device__ __forceinline__ float leaky(float v) { return v > 0.f ? v : NEG_SLOPE * v; }

__device__ __forceinline__ float red64(float v) {
#pragma unroll
    for (int off = 32; off > 0; off >>= 1) v += __shfl_xor(v, off, 64);
    return v;
}
__device__ __forceinline__ float red16(float v) {
#pragma unroll
    for (int off = 8; off > 0; off >>= 1) v += __shfl_xor(v, off, 64);
    return v;
}

// ---------------- MFMA GEMM 1: h_bf[N,64] = x[N,128] @ W1, + fused alpha ----------------
__global__ __launch_bounds__(128) void gemm1_kernel(const void* __restrict__ x,
                                                    const unsigned short* __restrict__ fw1,
                                                    const float* __restrict__ prm,
                                                    const int* __restrict__ flag,
                                                    unsigned short* __restrict__ h_bf,
                                                    float* __restrict__ as_,
                                                    float* __restrict__ ad_) {
    __shared__ short lx[2 * 4 * 64 * 8];   // 8 KB
    int t = threadIdx.x;
    int f = *flag;
    int base = blockIdx.x * 32;

#pragma unroll
    for (int i = 0; i < 4; ++i) {
        int cid = i * 128 + t;
        int m = cid >> 4, c = cid & 15;
        int q = c >> 2, g = c & 3;
        int loff = (((m >> 4) * 4 + q) * 64 + g * 16 + (m & 15)) * 8;
        short8 s;
        if (f) {
            const float4* p = (const float4*)((const float*)x + ((size_t)(base + m) << 7) + (c << 3));
            float4 u0 = p[0], u1 = p[1];
            s[0] = (short)f2bf(u0.x); s[1] = (short)f2bf(u0.y);
            s[2] = (short)f2bf(u0.z); s[3] = (short)f2bf(u0.w);
            s[4] = (short)f2bf(u1.x); s[5] = (short)f2bf(u1.y);
            s[6] = (short)f2bf(u1.z); s[7] = (short)f2bf(u1.w);
        } else {
            s = *(const short8*)((const unsigned short*)x + ((size_t)(base + m) << 7) + (c << 3));
        }
        *(short8*)&lx[loff] = s;
    }
    __syncthreads();

    int w = t >> 6, lane = t & 63;
    short8 a[4];
#pragma unroll
    for (int q = 0; q < 4; ++q) a[q] = *(short8*)&lx[((w * 4 + q) * 64 + lane) * 8];

    const short8* bw = (const short8*)fw1;
    floatx4 acc[4];
#pragma unroll
    for (int tt = 0; tt < 4; ++tt) acc[tt] = (floatx4){0.f, 0.f, 0.f, 0.f};
#pragma unroll
    for (int tt = 0; tt < 4; ++tt) {
#pragma unroll
        for (int q = 0; q < 4; ++q) {
            short8 b = bw[(tt * 4 + q) * 64 + lane];
            acc[tt] = __builtin_amdgcn_mfma_f32_16x16x32_bf16(a[q], b, acc[tt], 0, 0, 0);
        }
    }

    int cl = lane & 15, grp = lane >> 4;
#pragma unroll
    for (int tt = 0; tt < 4; ++tt) {
#pragma unroll
        for (int r = 0; r < 4; ++r) {
            int node = base + w * 16 + grp * 4 + r;
            h_bf[(size_t)node * 64 + tt * 16 + cl] = f2bf(acc[tt][r]);
        }
    }

    float as0 = prm[P_AS1 + 0  + cl], as1 = prm[P_AS1 + 16 + cl],
          as2 = prm[P_AS1 + 32 + cl], as3 = prm[P_AS1 + 48 + cl];
    float ad0 = prm[P_AD1 + 0  + cl], ad1 = prm[P_AD1 + 16 + cl],
          ad2 = prm[P_AD1 + 32 + cl], ad3 = prm[P_AD1 + 48 + cl];
#pragma unroll
    for (int r = 0; r < 4; ++r) {
        float sh0 = red16(acc[0][r] * as0 + acc[1][r] * as1);
        float sh1 = red16(acc[2][r] * as2 + acc[3][r] * as3);
        float dh0 = red16(acc[0][r] * ad0 + acc[1][r] * ad1);
        float dh1 = red16(acc[2][r] * ad2 + acc[3][r] * ad3);
        if (cl == 0) {
            int node = base + w * 16 + grp * 4 + r;
            as_[node * 2] = sh0;  as_[node * 2 + 1] = sh1;
            ad_[node * 2] = dh0;  ad_[node * 2 + 1] = dh1;
        }
    }
}

// ---------------- MFMA GEMM 2: h_bf = x1_bf[N,64] @ W2, + fused alpha ----------------
__global__ __launch_bounds__(128) void gemm2_kernel(const unsigned short* __restrict__ x1_bf,
                                                    const unsigned short* __restrict__ fw2,
                                                    const float* __restrict__ prm,
                                                    unsigned short* __restrict__ h_bf,
                                                    float* __restrict__ as_,
                                                    float* __restrict__ ad_) {
    __shared__ short lx[2 * 2 * 64 * 8];   // 4 KB
    int t = threadIdx.x;
    int base = blockIdx.x * 32;

#pragma unroll
    for (int i = 0; i < 2; ++i) {
        int cid = i * 128 + t;
        int m = cid >> 3, c = cid & 7;
        int q = c >> 2, g = c & 3;
        int loff = (((m >> 4) * 2 + q) * 64 + g * 16 + (m & 15)) * 8;
        short8 s = *(const short8*)(x1_bf + ((size_t)(base + m) << 6) + (c << 3));
        *(short8*)&lx[loff] = s;
    }
    __syncthreads();

    int w = t >> 6, lane = t & 63;
    short8 a[2];
#pragma unroll
    for (int q = 0; q < 2; ++q) a[q] = *(short8*)&lx[((w * 2 + q) * 64 + lane) * 8];

    const short8* bw = (const short8*)fw2;
    floatx4 acc[4];
#pragma unroll
    for (int tt = 0; tt < 4; ++tt) acc[tt] = (floatx4){0.f, 0.f, 0.f, 0.f};
#pragma unroll
    for (int tt = 0; tt < 4; ++tt) {
#pragma unroll
        for (int q = 0; q < 2; ++q) {
            short8 b = bw[(tt * 2 + q) * 64 + lane];
            acc[tt] = __builtin_amdgcn_mfma_f32_16x16x32_bf16(a[q], b, acc[tt], 0, 0, 0);
        }
    }

    int cl = lane & 15, grp = lane >> 4;
#pragma unroll
    for (int tt = 0; tt < 4; ++tt) {
#pragma unroll
        for (int r = 0; r < 4; ++r) {
            int node = base + w * 16 + grp * 4 + r;
            h_bf[(size_t)node * 64 + tt * 16 + cl] = f2bf(acc[tt][r]);
        }
    }

    float as0 = prm[P_AS2 + 0  + cl], as1 = prm[P_AS2 + 16 + cl],
          as2 = prm[P_AS2 + 32 + cl], as3 = prm[P_AS2 + 48 + cl];
    float ad0 = prm[P_AD2 + 0  + cl], ad1 = prm[P_AD2 + 16 + cl],
          ad2 = prm[P_AD2 + 32 + cl], ad3 = prm[P_AD2 + 48 + cl];
#pragma unroll
    for (int r = 0; r < 4; ++r) {
        float sh0 = red16(acc[0][r] * as0 + acc[1][r] * as1);
        float sh1 = red16(acc[2][r] * as2 + acc[3][r] * as3);
        float dh0 = red16(acc[0][r] * ad0 + acc[1][r] * ad1);
        float dh1 = red16(acc[2][r] * ad2 + acc[3][r] * ad3);
        if (cl == 0) {
            int node = base + w * 16 + grp * 4 + r;
            as_[node * 2] = sh0;  as_[node * 2 + 1] = sh1;
            ad_[node * 2] = dh0;  ad_[node * 2 + 1] = dh1;
        }
    }
}

// ---------------- aggregation core, slot-parallel ----------------
__device__ __forceinline__ float agg_core(const unsigned short* __restrict__ h_bf,
                                          const float* __restrict__ as_,
                                          const float* __restrict__ ad_,
                                          const int* __restrict__ col,
                                          int v, int rs, int re, int lane) {
    int head = lane >> 5;
    float adv0 = ad_[v * 2], adv1 = ad_[v * 2 + 1];
    int deg = re - rs;
    if (deg <= 64) {
        int sj = 0;
        float w0 = 0.f, w1 = 0.f;
        if (lane < deg) {
            sj = col[rs + lane];
            float2 av = *(const float2*)&as_[sj * 2];
            w0 = __expf(leaky(av.x + adv0));
            w1 = __expf(leaky(av.y + adv1));
        }
        float s0 = red64(w0), s1 = red64(w1);
        float rdh = 1.f / ((head ? s1 : s0) + 1e-16f);

        int slot = lane & 7;
        int cg   = lane >> 3;
        bool hi  = cg >= 4;
        float acc[8] = {0.f,0.f,0.f,0.f,0.f,0.f,0.f,0.f};
        int nit = (deg + 7) >> 3;

        auto body = [&](int g) {
            int j = g * 8 + slot;
            int sA   = __shfl(sj, j, 64);
            float wa = __shfl(w0, j, 64);
            float wb = __shfl(w1, j, 64);
            float w  = hi ? wb : wa;
            const uint4* p = (const uint4*)(h_bf + ((size_t)sA << 6) + (cg << 3));
            uint4 d = *p;
#pragma unroll
            for (int q = 0; q < 4; ++q) {
                unsigned int dw = (&d.x)[q];
                float lo  = __uint_as_float(dw << 16);
                float hif = __uint_as_float(dw & 0xFFFF0000u);
                acc[2 * q]     = fmaf(w, lo,  acc[2 * q]);
                acc[2 * q + 1] = fmaf(w, hif, acc[2 * q + 1]);
            }
        };
        int g = 0;
        for (; g + 1 < nit; g += 2) { body(g); body(g + 1); }
        if (g < nit) body(g);

#pragma unroll
        for (int m = 1; m <= 4; m <<= 1) {
#pragma unroll
            for (int q = 0; q < 8; ++q) acc[q] += __shfl_xor(acc[q], m, 64);
        }
        int k = lane & 7;
        float val = acc[0];
#pragma unroll
        for (int q = 1; q < 8; ++q) val = (k == q) ? acc[q] : val;
        return val * rdh;
    } else {
        float advh = head ? adv1 : adv0;
        float s0 = 0.f, s1 = 0.f;
        for (int e = rs + lane; e < re; e += 64) {
            int s = col[e];
            float2 av = *(const float2*)&as_[s * 2];
            s0 += __expf(leaky(av.x + adv0));
            s1 += __expf(leaky(av.y + adv1));
        }
        s0 = red64(s0); s1 = red64(s1);
        float rdh = 1.f / ((head ? s1 : s0) + 1e-16f);
        float a0 = 0.f;
        for (int e = rs; e < re; ++e) {
            int s = col[e];
            float w = __expf(leaky(as_[s * 2 + head] + advh));
            unsigned short u = h_bf[(size_t)s * 64 + lane];
            a0 = fmaf(w, __uint_as_float(((unsigned int)u) << 16), a0);
        }
        return a0 * rdh;
    }
}

// ---------------- aggregation layer 1 (+bias, BN eval, ELU) -> x1_bf ----------------
__global__ __launch_bounds__(256) void agg1_kernel(const unsigned short* __restrict__ h_bf,
                                                   const float* __restrict__ as_,
                                                   const float* __restrict__ ad_,
                                                   const int* __restrict__ row_start,
                                                   const int* __restrict__ col,
                                                   const float* __restrict__ bias,
                                                   const float* __restrict__ bn_g,
                                                   const float* __restrict__ bn_b,
                                                   const float* __restrict__ bn_m,
                                                   const float* __restrict__ bn_v,
                                                   unsigned short* __restrict__ x1_bf) {
    int t = threadIdx.x, wid = t >> 6, lane = t & 63;
    int v = blockIdx.x * 4 + wid;
    int rs = row_start[v], re = row_start[v + 1];
    float acc = agg_core(h_bf, as_, ad_, col, v, rs, re, lane);
    float r = acc + bias[lane];
    float scale = bn_g[lane] * rsqrtf(bn_v[lane] + BN_EPS);
    r = (r - bn_m[lane]) * scale + bn_b[lane];
    r = r > 0.f ? r : expm1f(r);   // ELU
    x1_bf[(size_t)v * 64 + lane] = f2bf(r);
}

// ---------------- aggregation layer 2 + JK max -> xj fp32 ----------------
__global__ __launch_bounds__(256) void agg2_kernel(const unsigned short* __restrict__ h_bf,
                                                   const float* __restrict__ as_,
                                                   const float* __restrict__ ad_,
                                                   const int* __restrict__ row_start,
                                                   const int* __restrict__ col,
                                                   const float* __restrict__ bias,
                                                   const unsigned short* __restrict__ x1_bf,
                                                   float* __restrict__ xj) {
    int t = threadIdx.x, wid = t >> 6, lane = t & 63;
    int v = blockIdx.x * 4 + wid;
    int rs = row_start[v], re = row_start[v + 1];
    float acc = agg_core(h_bf, as_, ad_, col, v, rs, re, lane);
    float x2 = acc + bias[lane];
    unsigned short u = x1_bf[(size_t)v * 64 + lane];
    float x1v = __uint_as_float(((unsigned int)u) << 16);
    xj[(size_t)v * 64 + lane] = fmaxf(x1v, x2);
}

// ---------------- final projection: out[N,40] = xj[N,64] @ Wf + bf ----------------
__global__ __launch_bounds__(320) void proj_kernel(const float* __restrict__ xj,
                                                   const float* __restrict__ Wf,
                                                   const float* __restrict__ bf_,
                                                   const int* __restrict__ flag,
                                                   void* __restrict__ out) {
    __shared__ float Wt[40 * 68];
    __shared__ float xs[8 * 64];
    int t = threadIdx.x;
    for (int i = t; i < 2560; i += 320) {
        int c = i / 40, o = i % 40;
        Wt[o * 68 + c] = Wf[i];
    }
    int base = blockIdx.x * 8;
    for (int i = t; i < 512; i += 320) xs[i] = xj[(size_t)base * 64 + i];
    __syncthreads();

    int n = t / 40, o = t % 40;
    float po = 0.f;
#pragma unroll
    for (int k = 0; k < 16; ++k) {
        float4 xv = *(const float4*)&xs[n * 64 + k * 4];
        float4 wv = *(const float4*)&Wt[o * 68 + k * 4];
        po = fmaf(xv.x, wv.x, fmaf(xv.y, wv.y, fmaf(xv.z, wv.z, fmaf(xv.w, wv.w, po))));
    }
    float r = po + bf_[o];
    size_t idx = (size_t)(base + n) * 40 + o;
    if (*flag) ((float*)out)[idx] = r;
    else ((__hip_bfloat16*)out)[idx] = __float2bfloat16(r);
}

extern "C" void kernel_launch(void* const* d_in, const int* in_sizes, int n_in,
                              void* d_out, int out_size, void* d_ws, size_t ws_size,
                              hipStream_t stream) {
    (void)in_sizes; (void)n_in; (void)out_size; (void)ws_size;
    const void* node_feat = d_in[0];
    const int*  edge_idx  = (const int*)d_in[1];

    char* ws = (char*)d_ws;
    size_t off = 0;
    auto alloc = [&](size_t bytes) -> void* {
        void* p = ws + off;
        off += (bytes + 255) & ~(size_t)255;
        return p;
    };
    unsigned short* h_bf  = (unsigned short*)alloc((size_t)N_NODES * 64 * 2);  // 12.8 MB
    unsigned short* x1_bf = (unsigned short*)alloc((size_t)N_NODES * 64 * 2);  // 12.8 MB
    float* xj  = (float*)alloc((size_t)N_NODES * 64 * 4);   // 25.6 MB
    float* as_ = (float*)alloc((size_t)N_NODES * 2 * 4);
    float* ad_ = (float*)alloc((size_t)N_NODES * 2 * 4);
    int* deg       = (int*)alloc((size_t)N_NODES * 4);
    int* row_start = (int*)alloc((size_t)(N_NODES + 1) * 4);
    int* cursor    = (int*)alloc((size_t)N_NODES * 4);
    int* col       = (int*)alloc((size_t)ETOT * 4);         // 6.8 MB
    int* bsum      = (int*)alloc((size_t)NB_SCAN * 4);
    int* boff      = (int*)alloc((size_t)NB_SCAN * 4);
    float* prm     = (float*)alloc((size_t)P_TOT * 4);
    unsigned short* fw1 = (unsigned short*)alloc(8192 * 2);
    unsigned short* fw2 = (unsigned short*)alloc(4096 * 2);
    int* flag      = (int*)alloc(256);

    detect_kernel<<<1, 64, 0, stream>>>((const unsigned short*)node_feat, flag);
    CvtArgs ca;
    const int lens[14] = {8192, 64, 64, 64, 64, 64, 64, 64, 4096, 64, 64, 64, 2560, 40};
    for (int i = 0; i < 14; ++i) { ca.ptr[i] = d_in[i + 2]; ca.len[i] = lens[i]; }
    cvt_params_kernel<<<(P_TOT + 255) / 256, 256, 0, stream>>>(ca, flag, prm);
    build_frags_kernel<<<48, 256, 0, stream>>>(prm, fw1, fw2);

    // CSR build: banded hist -> scan (+1 self-loop) -> banded scatter
    hipMemsetAsync(deg, 0, (size_t)N_NODES * 4, stream);
    hist_kernel<<<N_SLICE * 8, 256, 0, stream>>>(edge_idx, deg);
    scanA_kernel<<<NB_SCAN, 256, 0, stream>>>(deg, bsum);
    scanB_kernel<<<1, 512, 0, stream>>>(bsum, boff, row_start);
    scanC_kernel<<<NB_SCAN, 256, 0, stream>>>(deg, boff, row_start, cursor, col);
    scatter_kernel<<<N_SLICE * 8, 256, 0, stream>>>(edge_idx, cursor, col);

    gemm1_kernel<<<N_NODES / 32, 128, 0, stream>>>(node_feat, fw1, prm, flag,
                                                   h_bf, as_, ad_);
    agg1_kernel<<<N_NODES / 4, 256, 0, stream>>>(h_bf, as_, ad_, row_start, col,
                                                 prm + P_B1, prm + P_BNG, prm + P_BNB,
                                                 prm + P_BNM, prm + P_BNV, x1_bf);
    gemm2_kernel<<<N_NODES / 32, 128, 0, stream>>>(x1_bf, fw2, prm,
                                                   h_bf, as_, ad_);
    agg2_kernel<<<N_NODES / 4, 256, 0, stream>>>(h_bf, as_, ad_, row_start, col,
                                                 prm + P_B2, x1_bf, xj);
    proj_kernel<<<N_NODES / 8, 320, 0, stream>>>(xj, prm + P_WF, prm + P_BF,
                                                 flag, d_out);
}

// Round 8
// 430.388 us; speedup vs baseline: 2.5129x; 1.0388x over previous
//
#include <hip/hip_runtime.h>
#include <hip/hip_bf16.h>

#define N_NODES 100000
#define E_EDGES 1600000
#define ETOT    1700000   // E + N self-loops
#define NB_SCAN 391       // ceil(N/256)
#define F_IN    128
#define HC      64
#define OUT_C   40
#define NEG_SLOPE 0.2f
#define BN_EPS  1e-5f

// destination banding for CSR build: 4 bands of 25K nodes (col window 1.7 MB
// + cursor 100 KB per band). R7 lesson: the dst read stream was evicting the
// dirty col lines -> nt loads keep the stream out of L2.
#define BAND_SZ 25000
#define N_BAND  4
#define SLICE_E 8192      // edges per block-slice
#define N_SLICE 196       // ceil(E_EDGES / SLICE_E)

// fp32 param block layout (element offsets)
#define P_W1   0
#define P_AS1  8192
#define P_AD1  8256
#define P_B1   8320
#define P_BNG  8384
#define P_BNB  8448
#define P_BNM  8512
#define P_BNV  8576
#define P_W2   8640
#define P_AS2  12736
#define P_AD2  12800
#define P_B2   12864
#define P_WF   12928
#define P_BF   15488
#define P_TOT  15528

typedef __attribute__((ext_vector_type(8))) short short8;
typedef __attribute__((ext_vector_type(4))) float floatx4;

__device__ __forceinline__ unsigned short f2bf(float f) {   // RNE fp32->bf16
    unsigned int u = __float_as_uint(f);
    unsigned int r = u + 0x7FFFu + ((u >> 16) & 1u);
    return (unsigned short)(r >> 16);
}

// ---------------- dtype detection ----------------
__global__ __launch_bounds__(64) void detect_kernel(const unsigned short* __restrict__ x,
                                                    int* __restrict__ flag) {
    int t = threadIdx.x;
    bool huge = false;
#pragma unroll
    for (int i = 0; i < 4; ++i) {
        unsigned short u = x[(t * 4 + i) * 2];
        float v = __uint_as_float(((unsigned int)u) << 16);
        if (!(fabsf(v) < 1e4f)) huge = true;
    }
    unsigned long long b = __ballot(huge);
    if (t == 0) *flag = (b != 0ull) ? 1 : 0;             // 1 => fp32 tensors
}

// ---------------- small-param conversion to fp32 ----------------
struct CvtArgs { const void* ptr[14]; int len[14]; };

__global__ __launch_bounds__(256) void cvt_params_kernel(CvtArgs a,
                                                         const int* __restrict__ flag,
                                                         float* __restrict__ dst) {
    int f = *flag;
    int i = blockIdx.x * 256 + threadIdx.x;
    if (i >= P_TOT) return;
    int k = 0, off = 0;
    while (i >= off + a.len[k]) { off += a.len[k]; ++k; }
    int j = i - off;
    float v = f ? ((const float*)a.ptr[k])[j]
                : __bfloat162float(((const __hip_bfloat16*)a.ptr[k])[j]);
    dst[i] = v;
}

// ---------------- W1/W2 -> bf16 MFMA B-fragment order ----------------
__global__ __launch_bounds__(256) void build_frags_kernel(const float* __restrict__ prm,
                                                          unsigned short* __restrict__ fw1,
                                                          unsigned short* __restrict__ fw2) {
    int i = blockIdx.x * 256 + threadIdx.x;
    if (i < 8192) {
        int j = i & 7, l = (i >> 3) & 63, q = (i >> 9) & 3, t = i >> 11;
        int k = q * 32 + (l >> 4) * 8 + j;
        int n = t * 16 + (l & 15);
        fw1[i] = f2bf(prm[P_W1 + k * 64 + n]);
    } else if (i < 12288) {
        int f = i - 8192;
        int j = f & 7, l = (f >> 3) & 63, q = (f >> 9) & 1, t = f >> 10;
        int k = q * 32 + (l >> 4) * 8 + j;
        int n = t * 16 + (l & 15);
        fw2[f] = f2bf(prm[P_W2 + k * 64 + n]);
    }
}

// ---------------- CSR build: banded histogram, nt edge reads ----------------
__global__ __launch_bounds__(256) void hist_kernel(const int* __restrict__ ei,
                                                   int* __restrict__ deg) {
    int band  = blockIdx.x & (N_BAND - 1);
    int slice = blockIdx.x / N_BAND;
    int blo = band * BAND_SZ, bhi = blo + BAND_SZ;
    const unsigned long long* dst2 = (const unsigned long long*)(ei + E_EDGES);
    int base4 = slice * (SLICE_E / 4);
#pragma unroll
    for (int it = 0; it < 8; ++it) {
        int i4 = base4 + it * 256 + threadIdx.x;
        if (i4 < E_EDGES / 4) {
            unsigned long long p0 = __builtin_nontemporal_load(&dst2[i4 * 2]);
            unsigned long long p1 = __builtin_nontemporal_load(&dst2[i4 * 2 + 1]);
            int d[4] = {(int)(p0 & 0xFFFFFFFFull), (int)(p0 >> 32),
                        (int)(p1 & 0xFFFFFFFFull), (int)(p1 >> 32)};
#pragma unroll
            for (int c = 0; c < 4; ++c)
                if (d[c] >= blo && d[c] < bhi) atomicAdd(&deg[d[c]], 1);
        }
    }
}

// parallel scan; degree counted as deg[i]+1 (self-loop folded in)
__global__ __launch_bounds__(256) void scanA_kernel(const int* __restrict__ deg,
                                                    int* __restrict__ bsum) {
    __shared__ int sm[256];
    int t = threadIdx.x;
    int i = blockIdx.x * 256 + t;
    sm[t] = (i < N_NODES) ? deg[i] + 1 : 0;
    __syncthreads();
    for (int off = 128; off > 0; off >>= 1) {
        if (t < off) sm[t] += sm[t + off];
        __syncthreads();
    }
    if (t == 0) bsum[blockIdx.x] = sm[0];
}

__global__ __launch_bounds__(512) void scanB_kernel(const int* __restrict__ bsum,
                                                    int* __restrict__ boff,
                                                    int* __restrict__ row_start) {
    __shared__ int sm[512];
    int t = threadIdx.x;
    int v = (t < NB_SCAN) ? bsum[t] : 0;
    sm[t] = v;
    __syncthreads();
    for (int off = 1; off < 512; off <<= 1) {
        int o = (t >= off) ? sm[t - off] : 0;
        __syncthreads();
        sm[t] += o;
        __syncthreads();
    }
    if (t < NB_SCAN) boff[t] = sm[t] - v;
    if (t == NB_SCAN - 1) row_start[N_NODES] = sm[t];   // == ETOT
}

__global__ __launch_bounds__(256) void scanC_kernel(const int* __restrict__ deg,
                                                    const int* __restrict__ boff,
                                                    int* __restrict__ row_start,
                                                    int* __restrict__ cursor,
                                                    int* __restrict__ col) {
    __shared__ int sm[256];
    int t = threadIdx.x;
    int i = blockIdx.x * 256 + t;
    int v = (i < N_NODES) ? deg[i] + 1 : 0;
    sm[t] = v;
    __syncthreads();
    for (int off = 1; off < 256; off <<= 1) {
        int o = (t >= off) ? sm[t - off] : 0;
        __syncthreads();
        sm[t] += o;
        __syncthreads();
    }
    if (i < N_NODES) {
        int excl = sm[t] - v + boff[blockIdx.x];
        row_start[i] = excl;
        cursor[i]    = excl + 1;   // slot 0 = self-loop
        col[excl]    = i;
    }
}

// ---------------- banded scatter, nt edge reads ----------------
__global__ __launch_bounds__(256) void scatter_kernel(const int* __restrict__ ei,
                                                      int* __restrict__ cursor,
                                                      int* __restrict__ col) {
    int band  = blockIdx.x & (N_BAND - 1);
    int slice = blockIdx.x / N_BAND;
    int blo = band * BAND_SZ, bhi = blo + BAND_SZ;
    const unsigned long long* dst2 = (const unsigned long long*)(ei + E_EDGES);
    int base4 = slice * (SLICE_E / 4);
#pragma unroll
    for (int it = 0; it < 8; ++it) {
        int i4 = base4 + it * 256 + threadIdx.x;
        if (i4 < E_EDGES / 4) {
            unsigned long long p0 = __builtin_nontemporal_load(&dst2[i4 * 2]);
            unsigned long long p1 = __builtin_nontemporal_load(&dst2[i4 * 2 + 1]);
            int d[4] = {(int)(p0 & 0xFFFFFFFFull), (int)(p0 >> 32),
                        (int)(p1 & 0xFFFFFFFFull), (int)(p1 >> 32)};
#pragma unroll
            for (int c = 0; c < 4; ++c) {
                if (d[c] >= blo && d[c] < bhi) {
                    int s = __builtin_nontemporal_load(ei + i4 * 4 + c);
                    int pos = atomicAdd(&cursor[d[c]], 1);
                    col[pos] = s;
                }
            }
        }
    }
}

__device__ __forceinline__ float leaky(float v) { return v > 0.f ? v : NEG_SLOPE * v; }

__device__ __forceinline__ float red64(float v) {
#pragma unroll
    for (int off = 32; off > 0; off >>= 1) v += __shfl_xor(v, off, 64);
    return v;
}
__device__ __forceinline__ float red16(float v) {
#pragma unroll
    for (int off = 8; off > 0; off >>= 1) v += __shfl_xor(v, off, 64);
    return v;
}

// ---------------- MFMA GEMM 1: h_bf[N,64] = x[N,128] @ W1, + fused alpha ----------------
__global__ __launch_bounds__(128) void gemm1_kernel(const void* __restrict__ x,
                                                    const unsigned short* __restrict__ fw1,
                                                    const float* __restrict__ prm,
                                                    const int* __restrict__ flag,
                                                    unsigned short* __restrict__ h_bf,
                                                    float* __restrict__ as_,
                                                    float* __restrict__ ad_) {
    __shared__ short lx[2 * 4 * 64 * 8];   // 8 KB
    int t = threadIdx.x;
    int f = *flag;
    int base = blockIdx.x * 32;

#pragma unroll
    for (int i = 0; i < 4; ++i) {
        int cid = i * 128 + t;
        int m = cid >> 4, c = cid & 15;
        int q = c >> 2, g = c & 3;
        int loff = (((m >> 4) * 4 + q) * 64 + g * 16 + (m & 15)) * 8;
        short8 s;
        if (f) {
            const float4* p = (const float4*)((const float*)x + ((size_t)(base + m) << 7) + (c << 3));
            float4 u0 = p[0], u1 = p[1];
            s[0] = (short)f2bf(u0.x); s[1] = (short)f2bf(u0.y);
            s[2] = (short)f2bf(u0.z); s[3] = (short)f2bf(u0.w);
            s[4] = (short)f2bf(u1.x); s[5] = (short)f2bf(u1.y);
            s[6] = (short)f2bf(u1.z); s[7] = (short)f2bf(u1.w);
        } else {
            s = *(const short8*)((const unsigned short*)x + ((size_t)(base + m) << 7) + (c << 3));
        }
        *(short8*)&lx[loff] = s;
    }
    __syncthreads();

    int w = t >> 6, lane = t & 63;
    short8 a[4];
#pragma unroll
    for (int q = 0; q < 4; ++q) a[q] = *(short8*)&lx[((w * 4 + q) * 64 + lane) * 8];

    const short8* bw = (const short8*)fw1;
    floatx4 acc[4];
#pragma unroll
    for (int tt = 0; tt < 4; ++tt) acc[tt] = (floatx4){0.f, 0.f, 0.f, 0.f};
#pragma unroll
    for (int tt = 0; tt < 4; ++tt) {
#pragma unroll
        for (int q = 0; q < 4; ++q) {
            short8 b = bw[(tt * 4 + q) * 64 + lane];
            acc[tt] = __builtin_amdgcn_mfma_f32_16x16x32_bf16(a[q], b, acc[tt], 0, 0, 0);
        }
    }

    int cl = lane & 15, grp = lane >> 4;
#pragma unroll
    for (int tt = 0; tt < 4; ++tt) {
#pragma unroll
        for (int r = 0; r < 4; ++r) {
            int node = base + w * 16 + grp * 4 + r;
            h_bf[(size_t)node * 64 + tt * 16 + cl] = f2bf(acc[tt][r]);
        }
    }

    float as0 = prm[P_AS1 + 0  + cl], as1 = prm[P_AS1 + 16 + cl],
          as2 = prm[P_AS1 + 32 + cl], as3 = prm[P_AS1 + 48 + cl];
    float ad0 = prm[P_AD1 + 0  + cl], ad1 = prm[P_AD1 + 16 + cl],
          ad2 = prm[P_AD1 + 32 + cl], ad3 = prm[P_AD1 + 48 + cl];
#pragma unroll
    for (int r = 0; r < 4; ++r) {
        float sh0 = red16(acc[0][r] * as0 + acc[1][r] * as1);
        float sh1 = red16(acc[2][r] * as2 + acc[3][r] * as3);
        float dh0 = red16(acc[0][r] * ad0 + acc[1][r] * ad1);
        float dh1 = red16(acc[2][r] * ad2 + acc[3][r] * ad3);
        if (cl == 0) {
            int node = base + w * 16 + grp * 4 + r;
            as_[node * 2] = sh0;  as_[node * 2 + 1] = sh1;
            ad_[node * 2] = dh0;  ad_[node * 2 + 1] = dh1;
        }
    }
}

// ---------------- MFMA GEMM 2: h_bf = x1_bf[N,64] @ W2, + fused alpha ----------------
__global__ __launch_bounds__(128) void gemm2_kernel(const unsigned short* __restrict__ x1_bf,
                                                    const unsigned short* __restrict__ fw2,
                                                    const float* __restrict__ prm,
                                                    unsigned short* __restrict__ h_bf,
                                                    float* __restrict__ as_,
                                                    float* __restrict__ ad_) {
    __shared__ short lx[2 * 2 * 64 * 8];   // 4 KB
    int t = threadIdx.x;
    int base = blockIdx.x * 32;

#pragma unroll
    for (int i = 0; i < 2; ++i) {
        int cid = i * 128 + t;
        int m = cid >> 3, c = cid & 7;
        int q = c >> 2, g = c & 3;
        int loff = (((m >> 4) * 2 + q) * 64 + g * 16 + (m & 15)) * 8;
        short8 s = *(const short8*)(x1_bf + ((size_t)(base + m) << 6) + (c << 3));
        *(short8*)&lx[loff] = s;
    }
    __syncthreads();

    int w = t >> 6, lane = t & 63;
    short8 a[2];
#pragma unroll
    for (int q = 0; q < 2; ++q) a[q] = *(short8*)&lx[((w * 2 + q) * 64 + lane) * 8];

    const short8* bw = (const short8*)fw2;
    floatx4 acc[4];
#pragma unroll
    for (int tt = 0; tt < 4; ++tt) acc[tt] = (floatx4){0.f, 0.f, 0.f, 0.f};
#pragma unroll
    for (int tt = 0; tt < 4; ++tt) {
#pragma unroll
        for (int q = 0; q < 2; ++q) {
            short8 b = bw[(tt * 2 + q) * 64 + lane];
            acc[tt] = __builtin_amdgcn_mfma_f32_16x16x32_bf16(a[q], b, acc[tt], 0, 0, 0);
        }
    }

    int cl = lane & 15, grp = lane >> 4;
#pragma unroll
    for (int tt = 0; tt < 4; ++tt) {
#pragma unroll
        for (int r = 0; r < 4; ++r) {
            int node = base + w * 16 + grp * 4 + r;
            h_bf[(size_t)node * 64 + tt * 16 + cl] = f2bf(acc[tt][r]);
        }
    }

    float as0 = prm[P_AS2 + 0  + cl], as1 = prm[P_AS2 + 16 + cl],
          as2 = prm[P_AS2 + 32 + cl], as3 = prm[P_AS2 + 48 + cl];
    float ad0 = prm[P_AD2 + 0  + cl], ad1 = prm[P_AD2 + 16 + cl],
          ad2 = prm[P_AD2 + 32 + cl], ad3 = prm[P_AD2 + 48 + cl];
#pragma unroll
    for (int r = 0; r < 4; ++r) {
        float sh0 = red16(acc[0][r] * as0 + acc[1][r] * as1);
        float sh1 = red16(acc[2][r] * as2 + acc[3][r] * as3);
        float dh0 = red16(acc[0][r] * ad0 + acc[1][r] * ad1);
        float dh1 = red16(acc[2][r] * ad2 + acc[3][r] * ad3);
        if (cl == 0) {
            int node = base + w * 16 + grp * 4 + r;
            as_[node * 2] = sh0;  as_[node * 2 + 1] = sh1;
            ad_[node * 2] = dh0;  ad_[node * 2 + 1] = dh1;
        }
    }
}

// halving slot-reduction: lane ends with channel k=(lane&7) summed over its
// octet's 8 slots. 7 shfl + 14 sel + 7 add (vs 24/24/7 full butterfly).
// All shuffles convergent.
__device__ __forceinline__ float slot_reduce(float acc[8], int lane) {
    int slot = lane & 7;
    bool b2 = (slot & 4) != 0;
#pragma unroll
    for (int q = 0; q < 4; ++q) {
        float send = b2 ? acc[q] : acc[q + 4];
        float recv = __shfl_xor(send, 4, 64);
        acc[q] = (b2 ? acc[q + 4] : acc[q]) + recv;
    }
    bool b1 = (slot & 2) != 0;
#pragma unroll
    for (int q = 0; q < 2; ++q) {
        float send = b1 ? acc[q] : acc[q + 2];
        float recv = __shfl_xor(send, 2, 64);
        acc[q] = (b1 ? acc[q + 2] : acc[q]) + recv;
    }
    bool b0 = (slot & 1) != 0;
    float send = b0 ? acc[0] : acc[1];
    float recv = __shfl_xor(send, 1, 64);
    return (b0 ? acc[1] : acc[0]) + recv;
}

// ---------------- aggregation core, slot-parallel ----------------
__device__ __forceinline__ float agg_core(const unsigned short* __restrict__ h_bf,
                                          const float* __restrict__ as_,
                                          const float* __restrict__ ad_,
                                          const int* __restrict__ col,
                                          int v, int rs, int re, int lane) {
    int head = lane >> 5;
    float adv0 = ad_[v * 2], adv1 = ad_[v * 2 + 1];
    int deg = re - rs;
    if (deg <= 64) {
        int sj = 0;
        float w0 = 0.f, w1 = 0.f;
        if (lane < deg) {
            sj = col[rs + lane];
            float2 av = *(const float2*)&as_[sj * 2];
            w0 = __expf(leaky(av.x + adv0));
            w1 = __expf(leaky(av.y + adv1));
        }
        float s0 = red64(w0), s1 = red64(w1);
        float rdh = 1.f / ((head ? s1 : s0) + 1e-16f);

        int slot = lane & 7;
        int cg   = lane >> 3;
        bool hi  = cg >= 4;
        float acc[8] = {0.f,0.f,0.f,0.f,0.f,0.f,0.f,0.f};
        int nit = (deg + 7) >> 3;

        auto body = [&](int g) {
            int j = g * 8 + slot;
            int sA   = __shfl(sj, j, 64);
            float wa = __shfl(w0, j, 64);
            float wb = __shfl(w1, j, 64);
            float w  = hi ? wb : wa;
            const uint4* p = (const uint4*)(h_bf + ((size_t)sA << 6) + (cg << 3));
            uint4 d = *p;
#pragma unroll
            for (int q = 0; q < 4; ++q) {
                unsigned int dw = (&d.x)[q];
                float lo  = __uint_as_float(dw << 16);
                float hif = __uint_as_float(dw & 0xFFFF0000u);
                acc[2 * q]     = fmaf(w, lo,  acc[2 * q]);
                acc[2 * q + 1] = fmaf(w, hif, acc[2 * q + 1]);
            }
        };
        int g = 0;
        for (; g + 1 < nit; g += 2) { body(g); body(g + 1); }
        if (g < nit) body(g);

        return slot_reduce(acc, lane) * rdh;
    } else {
        float advh = head ? adv1 : adv0;
        float s0 = 0.f, s1 = 0.f;
        for (int e = rs + lane; e < re; e += 64) {
            int s = col[e];
            float2 av = *(const float2*)&as_[s * 2];
            s0 += __expf(leaky(av.x + adv0));
            s1 += __expf(leaky(av.y + adv1));
        }
        s0 = red64(s0); s1 = red64(s1);
        float rdh = 1.f / ((head ? s1 : s0) + 1e-16f);
        float a0 = 0.f;
        for (int e = rs; e < re; ++e) {
            int s = col[e];
            float w = __expf(leaky(as_[s * 2 + head] + advh));
            unsigned short u = h_bf[(size_t)s * 64 + lane];
            a0 = fmaf(w, __uint_as_float(((unsigned int)u) << 16), a0);
        }
        return a0 * rdh;
    }
}

// ---------------- aggregation layer 1 (+bias, BN eval, ELU) -> x1_bf ----------------
__global__ __launch_bounds__(256) void agg1_kernel(const unsigned short* __restrict__ h_bf,
                                                   const float* __restrict__ as_,
                                                   const float* __restrict__ ad_,
                                                   const int* __restrict__ row_start,
                                                   const int* __restrict__ col,
                                                   const float* __restrict__ bias,
                                                   const float* __restrict__ bn_g,
                                                   const float* __restrict__ bn_b,
                                                   const float* __restrict__ bn_m,
                                                   const float* __restrict__ bn_v,
                                                   unsigned short* __restrict__ x1_bf) {
    int t = threadIdx.x, wid = t >> 6, lane = t & 63;
    int v = blockIdx.x * 4 + wid;
    int rs = row_start[v], re = row_start[v + 1];
    float acc = agg_core(h_bf, as_, ad_, col, v, rs, re, lane);
    float r = acc + bias[lane];
    float scale = bn_g[lane] * rsqrtf(bn_v[lane] + BN_EPS);
    r = (r - bn_m[lane]) * scale + bn_b[lane];
    r = r > 0.f ? r : expm1f(r);   // ELU
    x1_bf[(size_t)v * 64 + lane] = f2bf(r);
}

// ---------------- agg layer 2 + JK max + fused projection -> out [N,40] ----------------
__global__ __launch_bounds__(256) void agg2_kernel(const unsigned short* __restrict__ h_bf,
                                                   const float* __restrict__ as_,
                                                   const float* __restrict__ ad_,
                                                   const int* __restrict__ row_start,
                                                   const int* __restrict__ col,
                                                   const float* __restrict__ prm,
                                                   const unsigned short* __restrict__ x1_bf,
                                                   const int* __restrict__ flag,
                                                   void* __restrict__ out) {
    __shared__ float Wfs[2560];      // Wf[c*40+o] natural layout: lanes o stride-1 -> conflict-free
    __shared__ float xsh[4][64];
    int t = threadIdx.x;
#pragma unroll
    for (int i = 0; i < 10; ++i) Wfs[i * 256 + t] = prm[P_WF + i * 256 + t];

    int wid = t >> 6, lane = t & 63;
    int v = blockIdx.x * 4 + wid;
    int rs = row_start[v], re = row_start[v + 1];
    float acc = agg_core(h_bf, as_, ad_, col, v, rs, re, lane);
    float x2 = acc + prm[P_B2 + lane];
    unsigned short u = x1_bf[(size_t)v * 64 + lane];
    float x1v = __uint_as_float(((unsigned int)u) << 16);
    xsh[wid][lane] = fmaxf(x1v, x2);   // JumpingKnowledge max
    __syncthreads();

    if (t < 160) {                     // 4 nodes x 40 outputs
        int n = t / 40, o = t - n * 40;
        float po = 0.f;
#pragma unroll
        for (int c = 0; c < 64; c += 4) {
            po = fmaf(xsh[n][c],     Wfs[c * 40 + o],       po);
            po = fmaf(xsh[n][c + 1], Wfs[(c + 1) * 40 + o], po);
            po = fmaf(xsh[n][c + 2], Wfs[(c + 2) * 40 + o], po);
            po = fmaf(xsh[n][c + 3], Wfs[(c + 3) * 40 + o], po);
        }
        float r = po + prm[P_BF + o];
        size_t idx = (size_t)(blockIdx.x * 4 + n) * 40 + o;
        if (*flag) ((float*)out)[idx] = r;
        else ((__hip_bfloat16*)out)[idx] = __float2bfloat16(r);
    }
}

extern "C" void kernel_launch(void* const* d_in, const int* in_sizes, int n_in,
                              void* d_out, int out_size, void* d_ws, size_t ws_size,
                              hipStream_t stream) {
    (void)in_sizes; (void)n_in; (void)out_size; (void)ws_size;
    const void* node_feat = d_in[0];
    const int*  edge_idx  = (const int*)d_in[1];

    char* ws = (char*)d_ws;
    size_t off = 0;
    auto alloc = [&](size_t bytes) -> void* {
        void* p = ws + off;
        off += (bytes + 255) & ~(size_t)255;
        return p;
    };
    unsigned short* h_bf  = (unsigned short*)alloc((size_t)N_NODES * 64 * 2);  // 12.8 MB
    unsigned short* x1_bf = (unsigned short*)alloc((size_t)N_NODES * 64 * 2);  // 12.8 MB
    float* as_ = (float*)alloc((size_t)N_NODES * 2 * 4);
    float* ad_ = (float*)alloc((size_t)N_NODES * 2 * 4);
    int* deg       = (int*)alloc((size_t)N_NODES * 4);
    int* row_start = (int*)alloc((size_t)(N_NODES + 1) * 4);
    int* cursor    = (int*)alloc((size_t)N_NODES * 4);
    int* col       = (int*)alloc((size_t)ETOT * 4);         // 6.8 MB
    int* bsum      = (int*)alloc((size_t)NB_SCAN * 4);
    int* boff      = (int*)alloc((size_t)NB_SCAN * 4);
    float* prm     = (float*)alloc((size_t)P_TOT * 4);
    unsigned short* fw1 = (unsigned short*)alloc(8192 * 2);
    unsigned short* fw2 = (unsigned short*)alloc(4096 * 2);
    int* flag      = (int*)alloc(256);

    detect_kernel<<<1, 64, 0, stream>>>((const unsigned short*)node_feat, flag);
    CvtArgs ca;
    const int lens[14] = {8192, 64, 64, 64, 64, 64, 64, 64, 4096, 64, 64, 64, 2560, 40};
    for (int i = 0; i < 14; ++i) { ca.ptr[i] = d_in[i + 2]; ca.len[i] = lens[i]; }
    cvt_params_kernel<<<(P_TOT + 255) / 256, 256, 0, stream>>>(ca, flag, prm);
    build_frags_kernel<<<48, 256, 0, stream>>>(prm, fw1, fw2);

    // CSR build: banded hist -> scan (+1 self-loop) -> banded scatter
    hipMemsetAsync(deg, 0, (size_t)N_NODES * 4, stream);
    hist_kernel<<<N_SLICE * N_BAND, 256, 0, stream>>>(edge_idx, deg);
    scanA_kernel<<<NB_SCAN, 256, 0, stream>>>(deg, bsum);
    scanB_kernel<<<1, 512, 0, stream>>>(bsum, boff, row_start);
    scanC_kernel<<<NB_SCAN, 256, 0, stream>>>(deg, boff, row_start, cursor, col);
    scatter_kernel<<<N_SLICE * N_BAND, 256, 0, stream>>>(edge_idx, cursor, col);

    gemm1_kernel<<<N_NODES / 32, 128, 0, stream>>>(node_feat, fw1, prm, flag,
                                                   h_bf, as_, ad_);
    agg1_kernel<<<N_NODES / 4, 256, 0, stream>>>(h_bf, as_, ad_, row_start, col,
                                                 prm + P_B1, prm + P_BNG, prm + P_BNB,
                                                 prm + P_BNM, prm + P_BNV, x1_bf);
    gemm2_kernel<<<N_NODES / 32, 128, 0, stream>>>(x1_bf, fw2, prm,
                                                   h_bf, as_, ad_);
    agg2_kernel<<<N_NODES / 4, 256, 0, stream>>>(h_bf, as_, ad_, row_start, col,
                                                 prm, x1_bf, flag, d_out);
}